// Round 7
// baseline (927.633 us; speedup 1.0000x reference)
//
#include <hip/hip_runtime.h>
#include <hip/hip_bf16.h>

typedef __hip_bfloat16 bf16;
typedef unsigned short u16;
typedef short short8 __attribute__((ext_vector_type(8)));
typedef float f32x4  __attribute__((ext_vector_type(4)));

static __device__ __forceinline__ float b2f(u16 u) {
    union { unsigned int i; float f; } c; c.i = (unsigned int)u << 16; return c.f;
}

// Runtime-dtype load/store: flag==1 -> bf16 inputs, 0 -> fp32 inputs.
static __device__ __forceinline__ float ldf(const void* p, size_t i, int isbf16) {
    return isbf16 ? __bfloat162float(((const bf16*)p)[i]) : ((const float*)p)[i];
}
static __device__ __forceinline__ void stf(void* p, size_t i, float v, int isbf16) {
    if (isbf16) ((bf16*)p)[i] = __float2bfloat16(v);
    else        ((float*)p)[i] = v;
}

// ---- split-bf16: v = hi + lo, both truncated bf16 ----
static __device__ __forceinline__ unsigned packf(float v) {
    unsigned ub = __float_as_uint(v);
    unsigned uh = ub & 0xFFFF0000u;
    float r = v - __uint_as_float(uh);
    return uh | (__float_as_uint(r) >> 16);
}
static __device__ __forceinline__ float unpackf(unsigned u) {
    return __uint_as_float(u & 0xFFFF0000u) + __uint_as_float(u << 16);
}

// unpack 8 packed u32 (two uint4) into hi-plane / lo-plane bf16x8
static __device__ __forceinline__ void upk8(uint4 a, uint4 b, short8& h, short8& l) {
    h = (short8){(short)(a.x >> 16), (short)(a.y >> 16), (short)(a.z >> 16), (short)(a.w >> 16),
                 (short)(b.x >> 16), (short)(b.y >> 16), (short)(b.z >> 16), (short)(b.w >> 16)};
    l = (short8){(short)(a.x), (short)(a.y), (short)(a.z), (short)(a.w),
                 (short)(b.x), (short)(b.y), (short)(b.z), (short)(b.w)};
}

// split 8 fp32 (two float4) into hi/lo bf16x8
static __device__ __forceinline__ void splitf8(float4 a, float4 b, short8& h, short8& l) {
    float vv[8] = {a.x, a.y, a.z, a.w, b.x, b.y, b.z, b.w};
    unsigned hh[8], ll[8];
#pragma unroll
    for (int j = 0; j < 8; j++) {
        unsigned ub = __float_as_uint(vv[j]);
        unsigned uh = ub & 0xFFFF0000u;
        float r = vv[j] - __uint_as_float(uh);
        hh[j] = uh >> 16;
        ll[j] = __float_as_uint(r) >> 16;
    }
    h = (short8){(short)hh[0], (short)hh[1], (short)hh[2], (short)hh[3],
                 (short)hh[4], (short)hh[5], (short)hh[6], (short)hh[7]};
    l = (short8){(short)ll[0], (short)ll[1], (short)ll[2], (short)ll[3],
                 (short)ll[4], (short)ll[5], (short)ll[6], (short)ll[7]};
}

static __device__ __forceinline__ float4 u2f4(uint4 a) {
    return (float4){__uint_as_float(a.x), __uint_as_float(a.y),
                    __uint_as_float(a.z), __uint_as_float(a.w)};
}
static __device__ __forceinline__ short8 u4_s8(uint4 a) {
    return (short8){(short)(a.x & 0xFFFF), (short)(a.x >> 16),
                    (short)(a.y & 0xFFFF), (short)(a.y >> 16),
                    (short)(a.z & 0xFFFF), (short)(a.z >> 16),
                    (short)(a.w & 0xFFFF), (short)(a.w >> 16)};
}

// mode: 0 = raw (fp32/bf16 per flag), 2 = packed u32
template<int MODE>
static __device__ __forceinline__ void load_any(const void* P, size_t e, int f, uint4* r) {
    if (MODE == 2) {
        const uint4* p = (const uint4*)((const unsigned*)P + e);
        r[0] = p[0]; r[1] = p[1]; r[2] = p[2]; r[3] = p[3];
    } else if (f == 0) {
        const uint4* p = (const uint4*)((const float*)P + e);
        r[0] = p[0]; r[1] = p[1]; r[2] = p[2]; r[3] = p[3];
    } else {
        const uint4* p = (const uint4*)((const u16*)P + e);
        r[0] = p[0]; r[1] = p[1];
        r[2] = (uint4){0, 0, 0, 0}; r[3] = (uint4){0, 0, 0, 0};
    }
}
template<int MODE>
static __device__ __forceinline__ void conv_any(const uint4* r, int f,
        short8& h0, short8& h1, short8& l0, short8& l1) {
    if (MODE == 2) {
        upk8(r[0], r[1], h0, l0);
        upk8(r[2], r[3], h1, l1);
    } else if (f == 0) {
        splitf8(u2f4(r[0]), u2f4(r[1]), h0, l0);
        splitf8(u2f4(r[2]), u2f4(r[3]), h1, l1);
    } else {
        h0 = u4_s8(r[0]); h1 = u4_s8(r[1]);
        l0 = (short8){0,0,0,0,0,0,0,0};
        l1 = (short8){0,0,0,0,0,0,0,0};
    }
}

static __device__ __forceinline__ void async_copy16(const void* g, void* l) {
    __builtin_amdgcn_global_load_lds((const __attribute__((address_space(1))) void*)g,
                                     (__attribute__((address_space(3))) void*)l, 16, 0, 0);
}

// ---------------------------------------------------------------------------
// dtype detection (verbatim)
// ---------------------------------------------------------------------------
__global__ void detect_dtype(const unsigned short* __restrict__ x, int n, int* __restrict__ flag)
{
    __shared__ int cnt;
    if (threadIdx.x == 0) cnt = 0;
    __syncthreads();
    int local = 0;
    for (int i = threadIdx.x; i < n; i += blockDim.x) {
        const unsigned int e = (x[i] >> 7) & 0xFF;
        if (e >= 134u) local++;
    }
    atomicAdd(&cnt, local);
    __syncthreads();
    if (threadIdx.x == 0) *flag = (cnt >= 32) ? 0 : 1;
}

// ---------------------------------------------------------------------------
// one-time split of x into hi/lo bf16 planes (memory-bound)
// ---------------------------------------------------------------------------
__global__ __launch_bounds__(256)
void split_x(const void* __restrict__ x, u16* __restrict__ Xh, u16* __restrict__ Xl,
             const int* __restrict__ flagp)
{
    const int f = *flagp;
    const size_t i = ((size_t)blockIdx.x * 256 + threadIdx.x) * 8;
    if (f == 0) {
        const float4* p = (const float4*)((const float*)x + i);
        short8 h, l;
        splitf8(p[0], p[1], h, l);
        *(short8*)(Xh + i) = h;
        *(short8*)(Xl + i) = l;
    } else {
        *(short8*)(Xh + i) = *(const short8*)((const u16*)x + i);
        *(short8*)(Xl + i) = (short8){0,0,0,0,0,0,0,0};
    }
}

// ---------------------------------------------------------------------------
// split-bf16 MFMA GEMM core.  C[m][n] = sum_k A[m][k]*B[n][k] + bias.
// AM/BM operand modes: 0 = raw (fp32/bf16 per flag) -> reg prefetch+split,
//                      1 = pre-split hi/lo planes  -> async global_load_lds,
//                      2 = packed u32              -> reg prefetch+unpack.
// OUT: 1 = packed u32, 2 = stf (dtype per flag),
//      4 = 16B-interleaved hi/lo planes ([row][col/8][{hi8,lo8}] u16).
// BROW: bias by output row.
// ---------------------------------------------------------------------------
template<int AM, int BM, int OUT, int BROW>
static __device__ __forceinline__ void gemm_core(
    const void* __restrict__ Aa, const void* __restrict__ Ab,
    const void* __restrict__ Ba, const void* __restrict__ Bb,
    const void* __restrict__ bias, void* __restrict__ Ca,
    int N, int K, int f, int bx, int by, u16* sm)
{
    u16* AhT = sm;
    u16* AlT = sm + 4096;
    u16* WhT = sm + 8192;
    u16* WlT = sm + 12288;

    const int t = threadIdx.x;
    const int w = t >> 6, lane = t & 63;
    const int wm = w >> 1, wn = w & 1;
    const int lr = lane & 15, quad = lane >> 4;
    const int bm = by * 128, bn = bx * 128;
    const int arow = lane >> 2;          // async map: row within 16-row chunk
    const int acol = (lane & 3) * 8;     // async map: col (u16 units)
    const int srow = t >> 1, scol = (t & 1) * 16;   // reg-staging map

    f32x4 acc[4][4];
#pragma unroll
    for (int i = 0; i < 4; i++)
#pragma unroll
        for (int j = 0; j < 4; j++) acc[i][j] = (f32x4){0.f, 0.f, 0.f, 0.f};

    // reg-side prefetch
    uint4 ra[4], rb[4];
    const size_t aBase = (size_t)(bm + srow) * K + scol;
    const size_t bBase = (size_t)(bn + srow) * K + scol;
    if (AM != 1) load_any<AM>(Aa, aBase, f, ra);
    if (BM != 1) load_any<BM>(Ba, bBase, f, rb);

    for (int k0 = 0; k0 < K; k0 += 32) {
        __syncthreads();
        if (AM == 1) {
#pragma unroll
            for (int c = 2 * w; c < 2 * w + 2; c++) {
                const int row = c * 16 + arow;
                async_copy16((const u16*)Aa + (size_t)(bm + row) * K + k0 + acol, &AhT[c * 512]);
                async_copy16((const u16*)Ab + (size_t)(bm + row) * K + k0 + acol, &AlT[c * 512]);
            }
        } else {
            short8 h0, h1, l0, l1;
            conv_any<AM>(ra, f, h0, h1, l0, l1);
            const int o = srow * 32 + scol;
            *(short8*)&AhT[o] = h0; *(short8*)&AhT[o + 8] = h1;
            *(short8*)&AlT[o] = l0; *(short8*)&AlT[o + 8] = l1;
        }
        if (BM == 1) {
#pragma unroll
            for (int c = 2 * w; c < 2 * w + 2; c++) {
                const int row = c * 16 + arow;
                async_copy16((const u16*)Ba + (size_t)(bn + row) * K + k0 + acol, &WhT[c * 512]);
                async_copy16((const u16*)Bb + (size_t)(bn + row) * K + k0 + acol, &WlT[c * 512]);
            }
        } else {
            short8 h0, h1, l0, l1;
            conv_any<BM>(rb, f, h0, h1, l0, l1);
            const int o = srow * 32 + scol;
            *(short8*)&WhT[o] = h0; *(short8*)&WhT[o + 8] = h1;
            *(short8*)&WlT[o] = l0; *(short8*)&WlT[o + 8] = l1;
        }
        __syncthreads();
        if (k0 + 32 < K) {
            if (AM != 1) load_any<AM>(Aa, aBase + k0 + 32, f, ra);
            if (BM != 1) load_any<BM>(Ba, bBase + k0 + 32, f, rb);
        }

        short8 avh[4], avl[4], bvh[4], bvl[4];
#pragma unroll
        for (int i = 0; i < 4; i++) {
            const int o = (wm * 64 + i * 16 + lr) * 32 + quad * 8;
            avh[i] = *(const short8*)&AhT[o];
            avl[i] = *(const short8*)&AlT[o];
        }
#pragma unroll
        for (int j = 0; j < 4; j++) {
            const int o = (wn * 64 + j * 16 + lr) * 32 + quad * 8;
            bvh[j] = *(const short8*)&WhT[o];
            bvl[j] = *(const short8*)&WlT[o];
        }
        __builtin_amdgcn_s_setprio(1);
        // product-outer: 16 independent MFMAs between dependent acc reuses
#pragma unroll
        for (int i = 0; i < 4; i++)
#pragma unroll
            for (int j = 0; j < 4; j++)
                acc[i][j] = __builtin_amdgcn_mfma_f32_16x16x32_bf16(avl[i], bvh[j], acc[i][j], 0, 0, 0);
#pragma unroll
        for (int i = 0; i < 4; i++)
#pragma unroll
            for (int j = 0; j < 4; j++)
                acc[i][j] = __builtin_amdgcn_mfma_f32_16x16x32_bf16(avh[i], bvl[j], acc[i][j], 0, 0, 0);
#pragma unroll
        for (int i = 0; i < 4; i++)
#pragma unroll
            for (int j = 0; j < 4; j++)
                acc[i][j] = __builtin_amdgcn_mfma_f32_16x16x32_bf16(avh[i], bvh[j], acc[i][j], 0, 0, 0);
        __builtin_amdgcn_s_setprio(0);
    }

#pragma unroll
    for (int j = 0; j < 4; j++) {
        const int col = bn + wn * 64 + j * 16 + lr;
        const float bc = BROW ? 0.f : ldf(bias, col, f);
#pragma unroll
        for (int i = 0; i < 4; i++) {
            const int row0 = bm + wm * 64 + i * 16 + quad * 4;
#pragma unroll
            for (int r = 0; r < 4; r++) {
                const int row = row0 + r;
                const float bb = BROW ? ldf(bias, row, f) : bc;
                const float val = acc[i][j][r] + bb;
                if (OUT == 1) {
                    ((unsigned*)Ca)[(size_t)row * N + col] = packf(val);
                } else if (OUT == 2) {
                    stf(Ca, (size_t)row * N + col, val, f);
                } else {   // OUT == 4: 16B-interleaved hi/lo planes
                    u16* C16 = (u16*)Ca;
                    const size_t ii = (size_t)row * ((size_t)N * 2)
                                    + ((size_t)(col >> 3) << 4) + (col & 7);
                    const unsigned ub = __float_as_uint(val);
                    const unsigned uh = ub & 0xFFFF0000u;
                    C16[ii]     = (u16)(uh >> 16);
                    C16[ii + 8] = (u16)(__float_as_uint(val - __uint_as_float(uh)) >> 16);
                }
            }
        }
    }
}

// fused Q (512) + K (128) + V^T (128) projections, x-side async from planes
__global__ __launch_bounds__(256, 3)
void gemm_qkv(const u16* __restrict__ Xh, const u16* __restrict__ Xl,
              const void* __restrict__ Wq, const void* __restrict__ bq, unsigned* __restrict__ Qp,
              const void* __restrict__ Wk, const void* __restrict__ bk, u16* __restrict__ Kil,
              const void* __restrict__ Wv, const void* __restrict__ bv, u16* __restrict__ Vtil,
              const int* __restrict__ flagp)
{
    __shared__ __align__(16) u16 sm[16384];
    const int f = *flagp;
    const int id = blockIdx.x;
    if (id < 512) {
        gemm_core<1, 0, 1, 0>(Xh, Xl, Wq, nullptr, bq, Qp,
                              2048, 2048, f, id & 15, id >> 4, sm);
    } else if (id < 640) {
        const int v = id - 512;
        gemm_core<1, 0, 4, 0>(Xh, Xl, Wk, nullptr, bk, Kil,
                              512, 2048, f, v & 3, v >> 2, sm);
    } else {
        const int v = id - 640;
        gemm_core<0, 1, 4, 1>(Wv, nullptr, Xh, Xl, bv, Vtil,
                              4096, 2048, f, v >> 2, v & 3, sm);
    }
}

// O-projection: ctx hi/lo planes (async global_load_lds) x raw Wo
__global__ __launch_bounds__(256, 3)
void gemm_o(const u16* __restrict__ Ch, const u16* __restrict__ Cl,
            const void* __restrict__ Wo, const void* __restrict__ bo,
            void* __restrict__ out, const int* __restrict__ flagp)
{
    __shared__ __align__(16) u16 sm[16384];
    gemm_core<1, 0, 2, 0>(Ch, Cl, Wo, nullptr, bo, out,
                          2048, 2048, *flagp, blockIdx.x & 15, blockIdx.x >> 4, sm);
}

// ---------------------------------------------------------------------------
// RMSnorm + RoPE (+gain*scale), in-place on packed Q
// ---------------------------------------------------------------------------
__global__ __launch_bounds__(64)
void norm_rope_pk(unsigned* __restrict__ buf, const void* __restrict__ gain,
                  int nheads, float scale, const int* __restrict__ flagp)
{
    const int id = blockIdx.x;
    const int h  = id % nheads;
    const int bs = id / nheads;
    const int s  = bs & 2047;
    unsigned* v = buf + (size_t)bs * nheads * 128 + h * 128;
    const int i = threadIdx.x;

    float t1 = unpackf(v[i]);
    float t2 = unpackf(v[i + 64]);
    float ss = t1 * t1 + t2 * t2;
#pragma unroll
    for (int off = 32; off >= 1; off >>= 1) ss += __shfl_xor(ss, off);
    const float r = rsqrtf(ss * (1.0f / 128.0f) + 1.1920929e-07f);
    t1 *= r; t2 *= r;

    const float inv_freq = exp2f(-(float)i * 0.20762050593046014f);
    const float ph = (float)s * inv_freq;
    float sn, cs;
    __sincosf(ph, &sn, &cs);

    float g = scale;
    if (gain) g *= ldf(gain, h, *flagp);

    v[i]      = packf((t1 * cs + t2 * sn) * g);
    v[i + 64] = packf((-t1 * sn + t2 * cs) * g);
}

// RMSnorm + RoPE in-place on 16B-interleaved K (scale=1, no gain).
// Element e of row: u16 addr = row*1024 + (c/8)*16 + c%8 (hi), +8 (lo).
__global__ __launch_bounds__(64)
void norm_rope_il(u16* __restrict__ buf, int nheads)
{
    const int id = blockIdx.x;
    const int h  = id % nheads;
    const int bs = id / nheads;
    const int s  = bs & 2047;
    u16* v = buf + (size_t)bs * (size_t)(nheads * 256);
    const int i = threadIdx.x;
    const int c1 = h * 128 + i;
    const int c2 = c1 + 64;
    const int a1 = ((c1 >> 3) << 4) + (c1 & 7);
    const int a2 = ((c2 >> 3) << 4) + (c2 & 7);

    float t1 = b2f(v[a1]) + b2f(v[a1 + 8]);
    float t2 = b2f(v[a2]) + b2f(v[a2 + 8]);
    float ss = t1 * t1 + t2 * t2;
#pragma unroll
    for (int off = 32; off >= 1; off >>= 1) ss += __shfl_xor(ss, off);
    const float r = rsqrtf(ss * (1.0f / 128.0f) + 1.1920929e-07f);
    t1 *= r; t2 *= r;

    const float inv_freq = exp2f(-(float)i * 0.20762050593046014f);
    const float ph = (float)s * inv_freq;
    float sn, cs;
    __sincosf(ph, &sn, &cs);

    const float o1 = t1 * cs + t2 * sn;
    const float o2 = -t1 * sn + t2 * cs;
    const unsigned u1 = __float_as_uint(o1) & 0xFFFF0000u;
    const unsigned u2 = __float_as_uint(o2) & 0xFFFF0000u;
    v[a1]     = (u16)(u1 >> 16);
    v[a1 + 8] = (u16)(__float_as_uint(o1 - __uint_as_float(u1)) >> 16);
    v[a2]     = (u16)(u2 >> 16);
    v[a2 + 8] = (u16)(__float_as_uint(o2 - __uint_as_float(u2)) >> 16);
}

// ---------------------------------------------------------------------------
// split-bf16 MFMA flash attention (round-3/5 structure; K/V in 16B-interleaved
// hi/lo format -> staging needs NO unpack; exact-skip rescale; plane C out).
// Qp:[4096][2048] packed u32, Kil:[4096][512] il, Vtil:[512][4096] il (V^T).
// grid (16, H, B): block x handles q-tiles x AND 31-x; 33 tile-units each.
// ---------------------------------------------------------------------------
__global__ __launch_bounds__(256, 2)
void attn3(const unsigned* __restrict__ Qp, const u16* __restrict__ Kil,
           const u16* __restrict__ Vtil,
           u16* __restrict__ Chg, u16* __restrict__ Clg)
{
    const int S = 2048, D = 2048;
    const int KVD2 = 1024;    // u16 per K row (512 cols * 2 planes)
    const int MT2  = 8192;    // u16 per V^T row (4096 cols * 2 planes)

    __shared__ __align__(16) u16 Kh[64 * 128], Kl[64 * 128];   // [k][d], XOR-swizzled
    __shared__ __align__(16) u16 Vh[128 * 64], Vl[128 * 64];   // [d][k], XOR-swizzled
    __shared__ __align__(16) u16 Ps[4][16][72];                // per-wave P plane

    const int t = threadIdx.x, w = t >> 6, lane = t & 63;
    const int lr = lane & 15, quad = lane >> 4;
    const int h = blockIdx.y, b = blockIdx.z;
    const int kvh = h >> 2;

    const int qt0 = blockIdx.x;          // 0..15
    const int qt1 = 31 - blockIdx.x;     // 16..31
    const int nt0 = qt0 + 1, nt1 = qt1 + 1;
    const int total = nt0 + nt1;         // 33 for every block

    // staging maps (interleaved: 8 consecutive uint4 = 4 groups of {hi16,lo16})
    const int kr = t >> 2, kq = t & 3;      // K: row 0..63, col-quarter
    const int vd = t >> 1, vh2 = t & 1;     // V^T: row (d) 0..127, col-half
    const u16* kg = Kil + (size_t)(b * S + kr) * KVD2 + kvh * 256 + kq * 64;
    const u16* vg = Vtil + (size_t)(kvh * 128 + vd) * MT2 + (size_t)(b * S) * 2 + vh2 * 64;
    char* KhB = (char*)Kh; char* KlB = (char*)Kl;
    char* VhB = (char*)Vh; char* VlB = (char*)Vl;

    uint4 kv[8], vv[8];
#define ISSUE_KV(K0)                                                          \
    do {                                                                      \
        _Pragma("unroll")                                                     \
        for (int u = 0; u < 8; u++) {                                         \
            kv[u] = *(const uint4*)(kg + (size_t)(K0) * KVD2 + u * 8);        \
            vv[u] = *(const uint4*)(vg + (size_t)(K0) * 2 + u * 8);           \
        }                                                                     \
    } while (0)

    short8 qh[4], ql[4];
    f32x4 acc[8];
    float mreg[4], lreg[4];
    int q0 = 0, nt = nt0;

    ISSUE_KV(0);

    for (int it = 0; it < total; it++) {
        const int item = (it >= nt0) ? 1 : 0;
        const int kt = item ? (it - nt0) : it;
        if (kt == 0) {
            nt = item ? nt1 : nt0;
            q0 = (item ? qt1 : qt0) * 64;
            const unsigned* qs = Qp + (size_t)(b * S + q0 + w * 16 + lr) * D + h * 128;
#pragma unroll
            for (int kk = 0; kk < 4; kk++) {
                const uint4* p = (const uint4*)(qs + kk * 32 + quad * 8);
                upk8(p[0], p[1], qh[kk], ql[kk]);
            }
#pragma unroll
            for (int dt = 0; dt < 8; dt++) acc[dt] = (f32x4){0.f, 0.f, 0.f, 0.f};
#pragma unroll
            for (int r = 0; r < 4; r++) { mreg[r] = -1e30f; lreg[r] = 0.f; }
        }
        const int k0 = kt * 64;

        __syncthreads();
        // prefetched regs -> swizzled LDS planes (no conversion!)
#pragma unroll
        for (int u2 = 0; u2 < 4; u2++) {
            const int ko = (kr * 256 + kq * 64 + u2 * 16) ^ ((kr & 7) << 4);
            *(uint4*)(KhB + ko) = kv[2 * u2];
            *(uint4*)(KlB + ko) = kv[2 * u2 + 1];
            const int vo = (vd * 128 + vh2 * 64 + u2 * 16) ^ ((vd & 7) << 4);
            *(uint4*)(VhB + vo) = vv[2 * u2];
            *(uint4*)(VlB + vo) = vv[2 * u2 + 1];
        }
        __syncthreads();

        // issue next tile's gathers; latency hides under compute below
        if (it + 1 < total) {
            const int nk0 = (it + 1 >= nt0) ? (it + 1 - nt0) * 64 : (it + 1) * 64;
            ISSUE_KV(nk0);
        }

        // S = Q*K^T  (3-product split; round-5 ordering)
        f32x4 sacc[4];
#pragma unroll
        for (int ct = 0; ct < 4; ct++) sacc[ct] = (f32x4){0.f, 0.f, 0.f, 0.f};
#pragma unroll
        for (int ks = 0; ks < 4; ks++) {
            short8 kbh[4], kbl[4];
#pragma unroll
            for (int ct = 0; ct < 4; ct++) {
                const int row = ct * 16 + lr;
                const int off = (row * 256 + ks * 64 + quad * 16) ^ ((row & 7) << 4);
                kbh[ct] = *(const short8*)(KhB + off);
                kbl[ct] = *(const short8*)(KlB + off);
            }
            __builtin_amdgcn_s_setprio(1);
#pragma unroll
            for (int ct = 0; ct < 4; ct++) {
                sacc[ct] = __builtin_amdgcn_mfma_f32_16x16x32_bf16(ql[ks], kbh[ct], sacc[ct], 0, 0, 0);
                sacc[ct] = __builtin_amdgcn_mfma_f32_16x16x32_bf16(qh[ks], kbl[ct], sacc[ct], 0, 0, 0);
                sacc[ct] = __builtin_amdgcn_mfma_f32_16x16x32_bf16(qh[ks], kbh[ct], sacc[ct], 0, 0, 0);
            }
            __builtin_amdgcn_s_setprio(0);
        }

        // online softmax; C-layout: row = quad*4+r, col = ct*16+lr
        const bool diag = (kt == nt - 1);
        float p[4][4];
#pragma unroll
        for (int r = 0; r < 4; r++) {
            const int qg = q0 + w * 16 + quad * 4 + r;
            float s0 = sacc[0][r], s1 = sacc[1][r], s2 = sacc[2][r], s3 = sacc[3][r];
            if (diag) {
                if (k0 +  0 + lr > qg) s0 = -1e30f;
                if (k0 + 16 + lr > qg) s1 = -1e30f;
                if (k0 + 32 + lr > qg) s2 = -1e30f;
                if (k0 + 48 + lr > qg) s3 = -1e30f;
            }
            float mt = fmaxf(fmaxf(s0, s1), fmaxf(s2, s3));
#pragma unroll
            for (int off = 1; off < 16; off <<= 1) mt = fmaxf(mt, __shfl_xor(mt, off));
            const float mnew  = fmaxf(mreg[r], mt);
            p[r][0] = (s0 <= -1e29f) ? 0.f : __expf(s0 - mnew);
            p[r][1] = (s1 <= -1e29f) ? 0.f : __expf(s1 - mnew);
            p[r][2] = (s2 <= -1e29f) ? 0.f : __expf(s2 - mnew);
            p[r][3] = (s3 <= -1e29f) ? 0.f : __expf(s3 - mnew);
            float ps = p[r][0] + p[r][1] + p[r][2] + p[r][3];
#pragma unroll
            for (int off = 1; off < 16; off <<= 1) ps += __shfl_xor(ps, off);
            if (mnew > mreg[r]) {   // exact skip: alpha==1 when max unchanged
                const float alpha = __expf(mreg[r] - mnew);
                lreg[r] = lreg[r] * alpha + ps;
                mreg[r] = mnew;
#pragma unroll
                for (int dt = 0; dt < 8; dt++) acc[dt][r] *= alpha;
            } else {
                lreg[r] += ps;
            }
        }

        // ---- PV pass 1: P_hi * (V_hi + V_lo), round-5 ordering ----
#pragma unroll
        for (int r = 0; r < 4; r++)
#pragma unroll
            for (int ct = 0; ct < 4; ct++)
                Ps[w][quad * 4 + r][ct * 16 + lr] = (u16)(__float_as_uint(p[r][ct]) >> 16);
#pragma unroll
        for (int ks2 = 0; ks2 < 2; ks2++) {
            const short8 pa = *(const short8*)((const char*)&Ps[w][lr][0] + ks2 * 64 + quad * 16);
            __builtin_amdgcn_s_setprio(1);
#pragma unroll
            for (int dt = 0; dt < 8; dt++) {
                const int vrow = dt * 16 + lr;
                const int off = (vrow * 128 + ks2 * 64 + quad * 16) ^ ((vrow & 7) << 4);
                const short8 vbh = *(const short8*)(VhB + off);
                const short8 vbl = *(const short8*)(VlB + off);
                acc[dt] = __builtin_amdgcn_mfma_f32_16x16x32_bf16(pa, vbh, acc[dt], 0, 0, 0);
                acc[dt] = __builtin_amdgcn_mfma_f32_16x16x32_bf16(pa, vbl, acc[dt], 0, 0, 0);
            }
            __builtin_amdgcn_s_setprio(0);
        }
        // ---- PV pass 2: P_lo * V_hi ----
#pragma unroll
        for (int r = 0; r < 4; r++)
#pragma unroll
            for (int ct = 0; ct < 4; ct++) {
                const unsigned ub = __float_as_uint(p[r][ct]);
                const unsigned uh = ub & 0xFFFF0000u;
                const float rr = p[r][ct] - __uint_as_float(uh);
                Ps[w][quad * 4 + r][ct * 16 + lr] = (u16)(__float_as_uint(rr) >> 16);
            }
#pragma unroll
        for (int ks2 = 0; ks2 < 2; ks2++) {
            const short8 pa = *(const short8*)((const char*)&Ps[w][lr][0] + ks2 * 64 + quad * 16);
            __builtin_amdgcn_s_setprio(1);
#pragma unroll
            for (int dt = 0; dt < 8; dt++) {
                const int vrow = dt * 16 + lr;
                const int off = (vrow * 128 + ks2 * 64 + quad * 16) ^ ((vrow & 7) << 4);
                const short8 vbh = *(const short8*)(VhB + off);
                acc[dt] = __builtin_amdgcn_mfma_f32_16x16x32_bf16(pa, vbh, acc[dt], 0, 0, 0);
            }
            __builtin_amdgcn_s_setprio(0);
        }

        // epilogue for the finished item -> hi/lo C planes
        if (kt == nt - 1) {
#pragma unroll
            for (int r = 0; r < 4; r++) {
                const float inv = 1.0f / lreg[r];
                const size_t base = (size_t)(b * S + q0 + w * 16 + quad * 4 + r) * D + h * 128 + lr;
#pragma unroll
                for (int dt = 0; dt < 8; dt++) {
                    const float val = acc[dt][r] * inv;
                    const unsigned ub = __float_as_uint(val);
                    const unsigned uh = ub & 0xFFFF0000u;
                    Chg[base + dt * 16] = (u16)(uh >> 16);
                    Clg[base + dt * 16] = (u16)(__float_as_uint(val - __uint_as_float(uh)) >> 16);
                }
            }
        }
    }
#undef ISSUE_KV
}

// ---------------------------------------------------------------------------
extern "C" void kernel_launch(void* const* d_in, const int* in_sizes, int n_in,
                              void* d_out, int out_size, void* d_ws, size_t ws_size,
                              hipStream_t stream)
{
    const void* x  = d_in[0];
    const void* Wq = d_in[1];
    const void* bq = d_in[2];
    const void* Wk = d_in[3];
    const void* bk = d_in[4];
    const void* Wv = d_in[5];
    const void* bv = d_in[6];
    const void* Wo = d_in[7];
    const void* bo = d_in[8];
    const void* qg = d_in[9];

    const int B = 2, S = 2048, D = 2048, H = 16, KVH = 4, KVD = 512;
    const int M = B * S;   // 4096

    // layout (83.9 MB, flag at the proven offset):
    //   Qp [M][D] u32 packed
    //   Kil  [M][KVD] 16B-interleaved hi/lo  (same bytes as u32-packed)
    //   Vtil [KVD][M] 16B-interleaved hi/lo  (V^T)
    //   C region: x hi/lo planes (pre-attn) -> ctx hi/lo planes (post-attn)
    unsigned* Qp  = (unsigned*)d_ws;              // [M][D]
    u16* Kil  = (u16*)(Qp + (size_t)M * D);       // M*KVD*2 u16
    u16* Vtil = Kil + (size_t)M * KVD * 2;        // KVD*M*2 u16
    u16* CXh  = Vtil + (size_t)KVD * M * 2;       // [M][D] hi plane
    u16* CXl  = CXh + (size_t)M * D;              // [M][D] lo plane
    int* flag = (int*)(CXl + (size_t)M * D);

    detect_dtype<<<1, 256, 0, stream>>>((const unsigned short*)x, 16384, flag);

    // one-time split of x into hi/lo planes (in the C region)
    split_x<<<(M * D) / (256 * 8), 256, 0, stream>>>(x, CXh, CXl, flag);

    // fused Q/K/V^T projections
    gemm_qkv<<<768, 256, 0, stream>>>(CXh, CXl, Wq, bq, Qp,
                                      Wk, bk, Kil, Wv, bv, Vtil, flag);

    // RMSnorm + RoPE in-place (scale*gain folded into Q)
    norm_rope_pk<<<M * H, 64, 0, stream>>>(Qp, qg, H, 0.08838834764831845f, flag);
    norm_rope_il<<<M * KVH, 64, 0, stream>>>(Kil, KVH);

    // attention: packed Q, interleaved K/V^T -> ctx hi/lo planes
    attn3<<<dim3(16, H, B), 256, 0, stream>>>(Qp, Kil, Vtil, CXh, CXl);

    // out = ctx*Wo^T + bo -> d_out (dtype follows input)
    gemm_o<<<512, 256, 0, stream>>>(CXh, CXl, Wo, bo, d_out, flag);
}

// Round 8
// 921.517 us; speedup vs baseline: 1.0066x; 1.0066x over previous
//
#include <hip/hip_runtime.h>
#include <hip/hip_bf16.h>

typedef __hip_bfloat16 bf16;
typedef unsigned short u16;
typedef short short8 __attribute__((ext_vector_type(8)));
typedef float f32x4  __attribute__((ext_vector_type(4)));

static __device__ __forceinline__ float b2f(u16 u) {
    union { unsigned int i; float f; } c; c.i = (unsigned int)u << 16; return c.f;
}

// Runtime-dtype load/store: flag==1 -> bf16 inputs, 0 -> fp32 inputs.
static __device__ __forceinline__ float ldf(const void* p, size_t i, int isbf16) {
    return isbf16 ? __bfloat162float(((const bf16*)p)[i]) : ((const float*)p)[i];
}
static __device__ __forceinline__ void stf(void* p, size_t i, float v, int isbf16) {
    if (isbf16) ((bf16*)p)[i] = __float2bfloat16(v);
    else        ((float*)p)[i] = v;
}

// ---- split-bf16: v = hi + lo, both truncated bf16 ----
static __device__ __forceinline__ unsigned packf(float v) {
    unsigned ub = __float_as_uint(v);
    unsigned uh = ub & 0xFFFF0000u;
    float r = v - __uint_as_float(uh);
    return uh | (__float_as_uint(r) >> 16);
}
static __device__ __forceinline__ float unpackf(unsigned u) {
    return __uint_as_float(u & 0xFFFF0000u) + __uint_as_float(u << 16);
}

// unpack 8 packed u32 (two uint4) into hi-plane / lo-plane bf16x8
static __device__ __forceinline__ void upk8(uint4 a, uint4 b, short8& h, short8& l) {
    h = (short8){(short)(a.x >> 16), (short)(a.y >> 16), (short)(a.z >> 16), (short)(a.w >> 16),
                 (short)(b.x >> 16), (short)(b.y >> 16), (short)(b.z >> 16), (short)(b.w >> 16)};
    l = (short8){(short)(a.x), (short)(a.y), (short)(a.z), (short)(a.w),
                 (short)(b.x), (short)(b.y), (short)(b.z), (short)(b.w)};
}

// split 8 fp32 (two float4) into hi/lo bf16x8
static __device__ __forceinline__ void splitf8(float4 a, float4 b, short8& h, short8& l) {
    float vv[8] = {a.x, a.y, a.z, a.w, b.x, b.y, b.z, b.w};
    unsigned hh[8], ll[8];
#pragma unroll
    for (int j = 0; j < 8; j++) {
        unsigned ub = __float_as_uint(vv[j]);
        unsigned uh = ub & 0xFFFF0000u;
        float r = vv[j] - __uint_as_float(uh);
        hh[j] = uh >> 16;
        ll[j] = __float_as_uint(r) >> 16;
    }
    h = (short8){(short)hh[0], (short)hh[1], (short)hh[2], (short)hh[3],
                 (short)hh[4], (short)hh[5], (short)hh[6], (short)hh[7]};
    l = (short8){(short)ll[0], (short)ll[1], (short)ll[2], (short)ll[3],
                 (short)ll[4], (short)ll[5], (short)ll[6], (short)ll[7]};
}

static __device__ __forceinline__ float4 u2f4(uint4 a) {
    return (float4){__uint_as_float(a.x), __uint_as_float(a.y),
                    __uint_as_float(a.z), __uint_as_float(a.w)};
}
static __device__ __forceinline__ short8 u4_s8(uint4 a) {
    return (short8){(short)(a.x & 0xFFFF), (short)(a.x >> 16),
                    (short)(a.y & 0xFFFF), (short)(a.y >> 16),
                    (short)(a.z & 0xFFFF), (short)(a.z >> 16),
                    (short)(a.w & 0xFFFF), (short)(a.w >> 16)};
}

// mode: 0 = raw (fp32/bf16 per flag), 2 = packed u32
template<int MODE>
static __device__ __forceinline__ void load_any(const void* P, size_t e, int f, uint4* r) {
    if (MODE == 2) {
        const uint4* p = (const uint4*)((const unsigned*)P + e);
        r[0] = p[0]; r[1] = p[1]; r[2] = p[2]; r[3] = p[3];
    } else if (f == 0) {
        const uint4* p = (const uint4*)((const float*)P + e);
        r[0] = p[0]; r[1] = p[1]; r[2] = p[2]; r[3] = p[3];
    } else {
        const uint4* p = (const uint4*)((const u16*)P + e);
        r[0] = p[0]; r[1] = p[1];
        r[2] = (uint4){0, 0, 0, 0}; r[3] = (uint4){0, 0, 0, 0};
    }
}
template<int MODE>
static __device__ __forceinline__ void conv_any(const uint4* r, int f,
        short8& h0, short8& h1, short8& l0, short8& l1) {
    if (MODE == 2) {
        upk8(r[0], r[1], h0, l0);
        upk8(r[2], r[3], h1, l1);
    } else if (f == 0) {
        splitf8(u2f4(r[0]), u2f4(r[1]), h0, l0);
        splitf8(u2f4(r[2]), u2f4(r[3]), h1, l1);
    } else {
        h0 = u4_s8(r[0]); h1 = u4_s8(r[1]);
        l0 = (short8){0,0,0,0,0,0,0,0};
        l1 = (short8){0,0,0,0,0,0,0,0};
    }
}

static __device__ __forceinline__ void async_copy16(const void* g, void* l) {
    __builtin_amdgcn_global_load_lds((const __attribute__((address_space(1))) void*)g,
                                     (__attribute__((address_space(3))) void*)l, 16, 0, 0);
}

// ---------------------------------------------------------------------------
// dtype detection (verbatim)
// ---------------------------------------------------------------------------
__global__ void detect_dtype(const unsigned short* __restrict__ x, int n, int* __restrict__ flag)
{
    __shared__ int cnt;
    if (threadIdx.x == 0) cnt = 0;
    __syncthreads();
    int local = 0;
    for (int i = threadIdx.x; i < n; i += blockDim.x) {
        const unsigned int e = (x[i] >> 7) & 0xFF;
        if (e >= 134u) local++;
    }
    atomicAdd(&cnt, local);
    __syncthreads();
    if (threadIdx.x == 0) *flag = (cnt >= 32) ? 0 : 1;
}

// ---------------------------------------------------------------------------
// one-time split of x into hi/lo bf16 planes (memory-bound)
// ---------------------------------------------------------------------------
__global__ __launch_bounds__(256)
void split_x(const void* __restrict__ x, u16* __restrict__ Xh, u16* __restrict__ Xl,
             const int* __restrict__ flagp)
{
    const int f = *flagp;
    const size_t i = ((size_t)blockIdx.x * 256 + threadIdx.x) * 8;
    if (f == 0) {
        const float4* p = (const float4*)((const float*)x + i);
        short8 h, l;
        splitf8(p[0], p[1], h, l);
        *(short8*)(Xh + i) = h;
        *(short8*)(Xl + i) = l;
    } else {
        *(short8*)(Xh + i) = *(const short8*)((const u16*)x + i);
        *(short8*)(Xl + i) = (short8){0,0,0,0,0,0,0,0};
    }
}

// ---------------------------------------------------------------------------
// split-bf16 MFMA GEMM core.  C[m][n] = sum_k A[m][k]*B[n][k] + bias.
// AM/BM operand modes: 0 = raw (fp32/bf16 per flag) -> reg prefetch+split,
//                      1 = pre-split hi/lo planes  -> async global_load_lds,
//                      2 = packed u32              -> reg prefetch+unpack.
// OUT: 1 = packed u32, 2 = stf (dtype per flag),
//      4 = 16B-interleaved hi/lo planes ([row][col/8][{hi8,lo8}] u16).
// BROW: bias by output row.
// ---------------------------------------------------------------------------
template<int AM, int BM, int OUT, int BROW>
static __device__ __forceinline__ void gemm_core(
    const void* __restrict__ Aa, const void* __restrict__ Ab,
    const void* __restrict__ Ba, const void* __restrict__ Bb,
    const void* __restrict__ bias, void* __restrict__ Ca,
    int N, int K, int f, int bx, int by, u16* sm)
{
    u16* AhT = sm;
    u16* AlT = sm + 4096;
    u16* WhT = sm + 8192;
    u16* WlT = sm + 12288;

    const int t = threadIdx.x;
    const int w = t >> 6, lane = t & 63;
    const int wm = w >> 1, wn = w & 1;
    const int lr = lane & 15, quad = lane >> 4;
    const int bm = by * 128, bn = bx * 128;
    const int arow = lane >> 2;          // async map: row within 16-row chunk
    const int acol = (lane & 3) * 8;     // async map: col (u16 units)
    const int srow = t >> 1, scol = (t & 1) * 16;   // reg-staging map

    f32x4 acc[4][4];
#pragma unroll
    for (int i = 0; i < 4; i++)
#pragma unroll
        for (int j = 0; j < 4; j++) acc[i][j] = (f32x4){0.f, 0.f, 0.f, 0.f};

    // reg-side prefetch
    uint4 ra[4], rb[4];
    const size_t aBase = (size_t)(bm + srow) * K + scol;
    const size_t bBase = (size_t)(bn + srow) * K + scol;
    if (AM != 1) load_any<AM>(Aa, aBase, f, ra);
    if (BM != 1) load_any<BM>(Ba, bBase, f, rb);

    for (int k0 = 0; k0 < K; k0 += 32) {
        __syncthreads();
        if (AM == 1) {
#pragma unroll
            for (int c = 2 * w; c < 2 * w + 2; c++) {
                const int row = c * 16 + arow;
                async_copy16((const u16*)Aa + (size_t)(bm + row) * K + k0 + acol, &AhT[c * 512]);
                async_copy16((const u16*)Ab + (size_t)(bm + row) * K + k0 + acol, &AlT[c * 512]);
            }
        } else {
            short8 h0, h1, l0, l1;
            conv_any<AM>(ra, f, h0, h1, l0, l1);
            const int o = srow * 32 + scol;
            *(short8*)&AhT[o] = h0; *(short8*)&AhT[o + 8] = h1;
            *(short8*)&AlT[o] = l0; *(short8*)&AlT[o + 8] = l1;
        }
        if (BM == 1) {
#pragma unroll
            for (int c = 2 * w; c < 2 * w + 2; c++) {
                const int row = c * 16 + arow;
                async_copy16((const u16*)Ba + (size_t)(bn + row) * K + k0 + acol, &WhT[c * 512]);
                async_copy16((const u16*)Bb + (size_t)(bn + row) * K + k0 + acol, &WlT[c * 512]);
            }
        } else {
            short8 h0, h1, l0, l1;
            conv_any<BM>(rb, f, h0, h1, l0, l1);
            const int o = srow * 32 + scol;
            *(short8*)&WhT[o] = h0; *(short8*)&WhT[o + 8] = h1;
            *(short8*)&WlT[o] = l0; *(short8*)&WlT[o + 8] = l1;
        }
        __syncthreads();
        if (k0 + 32 < K) {
            if (AM != 1) load_any<AM>(Aa, aBase + k0 + 32, f, ra);
            if (BM != 1) load_any<BM>(Ba, bBase + k0 + 32, f, rb);
        }

        short8 avh[4], avl[4], bvh[4], bvl[4];
#pragma unroll
        for (int i = 0; i < 4; i++) {
            const int o = (wm * 64 + i * 16 + lr) * 32 + quad * 8;
            avh[i] = *(const short8*)&AhT[o];
            avl[i] = *(const short8*)&AlT[o];
        }
#pragma unroll
        for (int j = 0; j < 4; j++) {
            const int o = (wn * 64 + j * 16 + lr) * 32 + quad * 8;
            bvh[j] = *(const short8*)&WhT[o];
            bvl[j] = *(const short8*)&WlT[o];
        }
        __builtin_amdgcn_s_setprio(1);
        // product-outer: 16 independent MFMAs between dependent acc reuses
#pragma unroll
        for (int i = 0; i < 4; i++)
#pragma unroll
            for (int j = 0; j < 4; j++)
                acc[i][j] = __builtin_amdgcn_mfma_f32_16x16x32_bf16(avl[i], bvh[j], acc[i][j], 0, 0, 0);
#pragma unroll
        for (int i = 0; i < 4; i++)
#pragma unroll
            for (int j = 0; j < 4; j++)
                acc[i][j] = __builtin_amdgcn_mfma_f32_16x16x32_bf16(avh[i], bvl[j], acc[i][j], 0, 0, 0);
#pragma unroll
        for (int i = 0; i < 4; i++)
#pragma unroll
            for (int j = 0; j < 4; j++)
                acc[i][j] = __builtin_amdgcn_mfma_f32_16x16x32_bf16(avh[i], bvh[j], acc[i][j], 0, 0, 0);
        __builtin_amdgcn_s_setprio(0);
    }

#pragma unroll
    for (int j = 0; j < 4; j++) {
        const int col = bn + wn * 64 + j * 16 + lr;
        const float bc = BROW ? 0.f : ldf(bias, col, f);
#pragma unroll
        for (int i = 0; i < 4; i++) {
            const int row0 = bm + wm * 64 + i * 16 + quad * 4;
#pragma unroll
            for (int r = 0; r < 4; r++) {
                const int row = row0 + r;
                const float bb = BROW ? ldf(bias, row, f) : bc;
                const float val = acc[i][j][r] + bb;
                if (OUT == 1) {
                    ((unsigned*)Ca)[(size_t)row * N + col] = packf(val);
                } else if (OUT == 2) {
                    stf(Ca, (size_t)row * N + col, val, f);
                } else {   // OUT == 4: 16B-interleaved hi/lo planes
                    u16* C16 = (u16*)Ca;
                    const size_t ii = (size_t)row * ((size_t)N * 2)
                                    + ((size_t)(col >> 3) << 4) + (col & 7);
                    const unsigned ub = __float_as_uint(val);
                    const unsigned uh = ub & 0xFFFF0000u;
                    C16[ii]     = (u16)(uh >> 16);
                    C16[ii + 8] = (u16)(__float_as_uint(val - __uint_as_float(uh)) >> 16);
                }
            }
        }
    }
}

// fused Q (512) + K (128) + V^T (128) projections, x-side async from planes
__global__ __launch_bounds__(256, 3)
void gemm_qkv(const u16* __restrict__ Xh, const u16* __restrict__ Xl,
              const void* __restrict__ Wq, const void* __restrict__ bq, unsigned* __restrict__ Qp,
              const void* __restrict__ Wk, const void* __restrict__ bk, u16* __restrict__ Kil,
              const void* __restrict__ Wv, const void* __restrict__ bv, u16* __restrict__ Vtil,
              const int* __restrict__ flagp)
{
    __shared__ __align__(16) u16 sm[16384];
    const int f = *flagp;
    const int id = blockIdx.x;
    if (id < 512) {
        gemm_core<1, 0, 1, 0>(Xh, Xl, Wq, nullptr, bq, Qp,
                              2048, 2048, f, id & 15, id >> 4, sm);
    } else if (id < 640) {
        const int v = id - 512;
        gemm_core<1, 0, 4, 0>(Xh, Xl, Wk, nullptr, bk, Kil,
                              512, 2048, f, v & 3, v >> 2, sm);
    } else {
        const int v = id - 640;
        gemm_core<0, 1, 4, 1>(Wv, nullptr, Xh, Xl, bv, Vtil,
                              4096, 2048, f, v >> 2, v & 3, sm);
    }
}

// O-projection: ctx hi/lo planes (async global_load_lds) x raw Wo
__global__ __launch_bounds__(256, 3)
void gemm_o(const u16* __restrict__ Ch, const u16* __restrict__ Cl,
            const void* __restrict__ Wo, const void* __restrict__ bo,
            void* __restrict__ out, const int* __restrict__ flagp)
{
    __shared__ __align__(16) u16 sm[16384];
    gemm_core<1, 0, 2, 0>(Ch, Cl, Wo, nullptr, bo, out,
                          2048, 2048, *flagp, blockIdx.x & 15, blockIdx.x >> 4, sm);
}

// ---------------------------------------------------------------------------
// RMSnorm + RoPE (+gain*scale), in-place on packed Q
// ---------------------------------------------------------------------------
__global__ __launch_bounds__(64)
void norm_rope_pk(unsigned* __restrict__ buf, const void* __restrict__ gain,
                  int nheads, float scale, const int* __restrict__ flagp)
{
    const int id = blockIdx.x;
    const int h  = id % nheads;
    const int bs = id / nheads;
    const int s  = bs & 2047;
    unsigned* v = buf + (size_t)bs * nheads * 128 + h * 128;
    const int i = threadIdx.x;

    float t1 = unpackf(v[i]);
    float t2 = unpackf(v[i + 64]);
    float ss = t1 * t1 + t2 * t2;
#pragma unroll
    for (int off = 32; off >= 1; off >>= 1) ss += __shfl_xor(ss, off);
    const float r = rsqrtf(ss * (1.0f / 128.0f) + 1.1920929e-07f);
    t1 *= r; t2 *= r;

    const float inv_freq = exp2f(-(float)i * 0.20762050593046014f);
    const float ph = (float)s * inv_freq;
    float sn, cs;
    __sincosf(ph, &sn, &cs);

    float g = scale;
    if (gain) g *= ldf(gain, h, *flagp);

    v[i]      = packf((t1 * cs + t2 * sn) * g);
    v[i + 64] = packf((-t1 * sn + t2 * cs) * g);
}

// RMSnorm + RoPE in-place on 16B-interleaved K (scale=1, no gain).
// Element e of row: u16 addr = row*1024 + (c/8)*16 + c%8 (hi), +8 (lo).
__global__ __launch_bounds__(64)
void norm_rope_il(u16* __restrict__ buf, int nheads)
{
    const int id = blockIdx.x;
    const int h  = id % nheads;
    const int bs = id / nheads;
    const int s  = bs & 2047;
    u16* v = buf + (size_t)bs * (size_t)(nheads * 256);
    const int i = threadIdx.x;
    const int c1 = h * 128 + i;
    const int c2 = c1 + 64;
    const int a1 = ((c1 >> 3) << 4) + (c1 & 7);
    const int a2 = ((c2 >> 3) << 4) + (c2 & 7);

    float t1 = b2f(v[a1]) + b2f(v[a1 + 8]);
    float t2 = b2f(v[a2]) + b2f(v[a2 + 8]);
    float ss = t1 * t1 + t2 * t2;
#pragma unroll
    for (int off = 32; off >= 1; off >>= 1) ss += __shfl_xor(ss, off);
    const float r = rsqrtf(ss * (1.0f / 128.0f) + 1.1920929e-07f);
    t1 *= r; t2 *= r;

    const float inv_freq = exp2f(-(float)i * 0.20762050593046014f);
    const float ph = (float)s * inv_freq;
    float sn, cs;
    __sincosf(ph, &sn, &cs);

    const float o1 = t1 * cs + t2 * sn;
    const float o2 = -t1 * sn + t2 * cs;
    const unsigned u1 = __float_as_uint(o1) & 0xFFFF0000u;
    const unsigned u2 = __float_as_uint(o2) & 0xFFFF0000u;
    v[a1]     = (u16)(u1 >> 16);
    v[a1 + 8] = (u16)(__float_as_uint(o1 - __uint_as_float(u1)) >> 16);
    v[a2]     = (u16)(u2 >> 16);
    v[a2 + 8] = (u16)(__float_as_uint(o2 - __uint_as_float(u2)) >> 16);
}

// ---------------------------------------------------------------------------
// split-bf16 MFMA flash attention.  Interleaved K/V staging (no unpack),
// BRANCHLESS online softmax (round-5 form — the r7 branch caused the
// prefetch-register spill), round-3/5 MFMA ordering, plane C epilogue.
// Qp:[4096][2048] packed u32, Kil:[4096][512] il, Vtil:[512][4096] il (V^T).
// grid (16, H, B): block x handles q-tiles x AND 31-x; 33 tile-units each.
// ---------------------------------------------------------------------------
__global__ __launch_bounds__(256, 2)
void attn3(const unsigned* __restrict__ Qp, const u16* __restrict__ Kil,
           const u16* __restrict__ Vtil,
           u16* __restrict__ Chg, u16* __restrict__ Clg)
{
    const int S = 2048, D = 2048;
    const int KVD2 = 1024;    // u16 per K row (512 cols * 2 planes)
    const int MT2  = 8192;    // u16 per V^T row (4096 cols * 2 planes)

    __shared__ __align__(16) u16 Kh[64 * 128], Kl[64 * 128];   // [k][d], XOR-swizzled
    __shared__ __align__(16) u16 Vh[128 * 64], Vl[128 * 64];   // [d][k], XOR-swizzled
    __shared__ __align__(16) u16 Ps[4][16][72];                // per-wave P plane

    const int t = threadIdx.x, w = t >> 6, lane = t & 63;
    const int lr = lane & 15, quad = lane >> 4;
    const int h = blockIdx.y, b = blockIdx.z;
    const int kvh = h >> 2;

    const int qt0 = blockIdx.x;          // 0..15
    const int qt1 = 31 - blockIdx.x;     // 16..31
    const int nt0 = qt0 + 1, nt1 = qt1 + 1;
    const int total = nt0 + nt1;         // 33 for every block

    // staging maps (interleaved: 8 consecutive uint4 = 4 groups of {hi16,lo16})
    const int kr = t >> 2, kq = t & 3;      // K: row 0..63, col-quarter
    const int vd = t >> 1, vh2 = t & 1;     // V^T: row (d) 0..127, col-half
    const u16* kg = Kil + (size_t)(b * S + kr) * KVD2 + kvh * 256 + kq * 64;
    const u16* vg = Vtil + (size_t)(kvh * 128 + vd) * MT2 + (size_t)(b * S) * 2 + vh2 * 64;
    char* KhB = (char*)Kh; char* KlB = (char*)Kl;
    char* VhB = (char*)Vh; char* VlB = (char*)Vl;

    uint4 kv[8], vv[8];
#define ISSUE_KV(K0)                                                          \
    do {                                                                      \
        _Pragma("unroll")                                                     \
        for (int u = 0; u < 8; u++) {                                         \
            kv[u] = *(const uint4*)(kg + (size_t)(K0) * KVD2 + u * 8);        \
            vv[u] = *(const uint4*)(vg + (size_t)(K0) * 2 + u * 8);           \
        }                                                                     \
    } while (0)

    short8 qh[4], ql[4];
    f32x4 acc[8];
    float mreg[4], lreg[4];
    int q0 = 0, nt = nt0;

    ISSUE_KV(0);

    for (int it = 0; it < total; it++) {
        const int item = (it >= nt0) ? 1 : 0;
        const int kt = item ? (it - nt0) : it;
        if (kt == 0) {
            nt = item ? nt1 : nt0;
            q0 = (item ? qt1 : qt0) * 64;
            const unsigned* qs = Qp + (size_t)(b * S + q0 + w * 16 + lr) * D + h * 128;
#pragma unroll
            for (int kk = 0; kk < 4; kk++) {
                const uint4* p = (const uint4*)(qs + kk * 32 + quad * 8);
                upk8(p[0], p[1], qh[kk], ql[kk]);
            }
#pragma unroll
            for (int dt = 0; dt < 8; dt++) acc[dt] = (f32x4){0.f, 0.f, 0.f, 0.f};
#pragma unroll
            for (int r = 0; r < 4; r++) { mreg[r] = -1e30f; lreg[r] = 0.f; }
        }
        const int k0 = kt * 64;

        __syncthreads();
        // prefetched regs -> swizzled LDS planes (no conversion!)
#pragma unroll
        for (int u2 = 0; u2 < 4; u2++) {
            const int ko = (kr * 256 + kq * 64 + u2 * 16) ^ ((kr & 7) << 4);
            *(uint4*)(KhB + ko) = kv[2 * u2];
            *(uint4*)(KlB + ko) = kv[2 * u2 + 1];
            const int vo = (vd * 128 + vh2 * 64 + u2 * 16) ^ ((vd & 7) << 4);
            *(uint4*)(VhB + vo) = vv[2 * u2];
            *(uint4*)(VlB + vo) = vv[2 * u2 + 1];
        }
        __syncthreads();

        // issue next tile's gathers; latency hides under compute below
        if (it + 1 < total) {
            const int nk0 = (it + 1 >= nt0) ? (it + 1 - nt0) * 64 : (it + 1) * 64;
            ISSUE_KV(nk0);
        }

        // S = Q*K^T  (3-product split; round-3/5 ordering)
        f32x4 sacc[4];
#pragma unroll
        for (int ct = 0; ct < 4; ct++) sacc[ct] = (f32x4){0.f, 0.f, 0.f, 0.f};
#pragma unroll
        for (int ks = 0; ks < 4; ks++) {
            short8 kbh[4], kbl[4];
#pragma unroll
            for (int ct = 0; ct < 4; ct++) {
                const int row = ct * 16 + lr;
                const int off = (row * 256 + ks * 64 + quad * 16) ^ ((row & 7) << 4);
                kbh[ct] = *(const short8*)(KhB + off);
                kbl[ct] = *(const short8*)(KlB + off);
            }
            __builtin_amdgcn_s_setprio(1);
#pragma unroll
            for (int ct = 0; ct < 4; ct++) {
                sacc[ct] = __builtin_amdgcn_mfma_f32_16x16x32_bf16(ql[ks], kbh[ct], sacc[ct], 0, 0, 0);
                sacc[ct] = __builtin_amdgcn_mfma_f32_16x16x32_bf16(qh[ks], kbl[ct], sacc[ct], 0, 0, 0);
                sacc[ct] = __builtin_amdgcn_mfma_f32_16x16x32_bf16(qh[ks], kbh[ct], sacc[ct], 0, 0, 0);
            }
            __builtin_amdgcn_s_setprio(0);
        }

        // online softmax (BRANCHLESS, round-5 form)
        const bool diag = (kt == nt - 1);
        float p[4][4];
#pragma unroll
        for (int r = 0; r < 4; r++) {
            const int qg = q0 + w * 16 + quad * 4 + r;
            float s0 = sacc[0][r], s1 = sacc[1][r], s2 = sacc[2][r], s3 = sacc[3][r];
            if (diag) {
                if (k0 +  0 + lr > qg) s0 = -1e30f;
                if (k0 + 16 + lr > qg) s1 = -1e30f;
                if (k0 + 32 + lr > qg) s2 = -1e30f;
                if (k0 + 48 + lr > qg) s3 = -1e30f;
            }
            float mt = fmaxf(fmaxf(s0, s1), fmaxf(s2, s3));
#pragma unroll
            for (int off = 1; off < 16; off <<= 1) mt = fmaxf(mt, __shfl_xor(mt, off));
            const float mnew  = fmaxf(mreg[r], mt);
            const float alpha = __expf(mreg[r] - mnew);
            p[r][0] = (s0 <= -1e29f) ? 0.f : __expf(s0 - mnew);
            p[r][1] = (s1 <= -1e29f) ? 0.f : __expf(s1 - mnew);
            p[r][2] = (s2 <= -1e29f) ? 0.f : __expf(s2 - mnew);
            p[r][3] = (s3 <= -1e29f) ? 0.f : __expf(s3 - mnew);
            float ps = p[r][0] + p[r][1] + p[r][2] + p[r][3];
#pragma unroll
            for (int off = 1; off < 16; off <<= 1) ps += __shfl_xor(ps, off);
            lreg[r] = lreg[r] * alpha + ps;
            mreg[r] = mnew;
#pragma unroll
            for (int dt = 0; dt < 8; dt++) acc[dt][r] *= alpha;
        }

        // ---- PV pass 1: P_hi * (V_hi + V_lo) ----
#pragma unroll
        for (int r = 0; r < 4; r++)
#pragma unroll
            for (int ct = 0; ct < 4; ct++)
                Ps[w][quad * 4 + r][ct * 16 + lr] = (u16)(__float_as_uint(p[r][ct]) >> 16);
#pragma unroll
        for (int ks2 = 0; ks2 < 2; ks2++) {
            const short8 pa = *(const short8*)((const char*)&Ps[w][lr][0] + ks2 * 64 + quad * 16);
            __builtin_amdgcn_s_setprio(1);
#pragma unroll
            for (int dt = 0; dt < 8; dt++) {
                const int vrow = dt * 16 + lr;
                const int off = (vrow * 128 + ks2 * 64 + quad * 16) ^ ((vrow & 7) << 4);
                const short8 vbh = *(const short8*)(VhB + off);
                const short8 vbl = *(const short8*)(VlB + off);
                acc[dt] = __builtin_amdgcn_mfma_f32_16x16x32_bf16(pa, vbh, acc[dt], 0, 0, 0);
                acc[dt] = __builtin_amdgcn_mfma_f32_16x16x32_bf16(pa, vbl, acc[dt], 0, 0, 0);
            }
            __builtin_amdgcn_s_setprio(0);
        }
        // ---- PV pass 2: P_lo * V_hi ----
#pragma unroll
        for (int r = 0; r < 4; r++)
#pragma unroll
            for (int ct = 0; ct < 4; ct++) {
                const unsigned ub = __float_as_uint(p[r][ct]);
                const unsigned uh = ub & 0xFFFF0000u;
                const float rr = p[r][ct] - __uint_as_float(uh);
                Ps[w][quad * 4 + r][ct * 16 + lr] = (u16)(__float_as_uint(rr) >> 16);
            }
#pragma unroll
        for (int ks2 = 0; ks2 < 2; ks2++) {
            const short8 pa = *(const short8*)((const char*)&Ps[w][lr][0] + ks2 * 64 + quad * 16);
            __builtin_amdgcn_s_setprio(1);
#pragma unroll
            for (int dt = 0; dt < 8; dt++) {
                const int vrow = dt * 16 + lr;
                const int off = (vrow * 128 + ks2 * 64 + quad * 16) ^ ((vrow & 7) << 4);
                const short8 vbh = *(const short8*)(VhB + off);
                acc[dt] = __builtin_amdgcn_mfma_f32_16x16x32_bf16(pa, vbh, acc[dt], 0, 0, 0);
            }
            __builtin_amdgcn_s_setprio(0);
        }

        // epilogue for the finished item -> hi/lo C planes
        if (kt == nt - 1) {
#pragma unroll
            for (int r = 0; r < 4; r++) {
                const float inv = 1.0f / lreg[r];
                const size_t base = (size_t)(b * S + q0 + w * 16 + quad * 4 + r) * D + h * 128 + lr;
#pragma unroll
                for (int dt = 0; dt < 8; dt++) {
                    const float val = acc[dt][r] * inv;
                    const unsigned ub = __float_as_uint(val);
                    const unsigned uh = ub & 0xFFFF0000u;
                    Chg[base + dt * 16] = (u16)(uh >> 16);
                    Clg[base + dt * 16] = (u16)(__float_as_uint(val - __uint_as_float(uh)) >> 16);
                }
            }
        }
    }
#undef ISSUE_KV
}

// ---------------------------------------------------------------------------
extern "C" void kernel_launch(void* const* d_in, const int* in_sizes, int n_in,
                              void* d_out, int out_size, void* d_ws, size_t ws_size,
                              hipStream_t stream)
{
    const void* x  = d_in[0];
    const void* Wq = d_in[1];
    const void* bq = d_in[2];
    const void* Wk = d_in[3];
    const void* bk = d_in[4];
    const void* Wv = d_in[5];
    const void* bv = d_in[6];
    const void* Wo = d_in[7];
    const void* bo = d_in[8];
    const void* qg = d_in[9];

    const int B = 2, S = 2048, D = 2048, H = 16, KVH = 4, KVD = 512;
    const int M = B * S;   // 4096

    // layout (83.9 MB, flag at the proven offset):
    //   Qp [M][D] u32 packed
    //   Kil  [M][KVD] 16B-interleaved hi/lo
    //   Vtil [KVD][M] 16B-interleaved hi/lo  (V^T)
    //   C region: x hi/lo planes (pre-attn) -> ctx hi/lo planes (post-attn)
    unsigned* Qp  = (unsigned*)d_ws;              // [M][D]
    u16* Kil  = (u16*)(Qp + (size_t)M * D);       // M*KVD*2 u16
    u16* Vtil = Kil + (size_t)M * KVD * 2;        // KVD*M*2 u16
    u16* CXh  = Vtil + (size_t)KVD * M * 2;       // [M][D] hi plane
    u16* CXl  = CXh + (size_t)M * D;              // [M][D] lo plane
    int* flag = (int*)(CXl + (size_t)M * D);

    detect_dtype<<<1, 256, 0, stream>>>((const unsigned short*)x, 16384, flag);

    // one-time split of x into hi/lo planes (in the C region)
    split_x<<<(M * D) / (256 * 8), 256, 0, stream>>>(x, CXh, CXl, flag);

    // fused Q/K/V^T projections
    gemm_qkv<<<768, 256, 0, stream>>>(CXh, CXl, Wq, bq, Qp,
                                      Wk, bk, Kil, Wv, bv, Vtil, flag);

    // RMSnorm + RoPE in-place (scale*gain folded into Q)
    norm_rope_pk<<<M * H, 64, 0, stream>>>(Qp, qg, H, 0.08838834764831845f, flag);
    norm_rope_il<<<M * KVH, 64, 0, stream>>>(Kil, KVH);

    // attention: packed Q, interleaved K/V^T -> ctx hi/lo planes
    attn3<<<dim3(16, H, B), 256, 0, stream>>>(Qp, Kil, Vtil, CXh, CXl);

    // out = ctx*Wo^T + bo -> d_out (dtype follows input)
    gemm_o<<<512, 256, 0, stream>>>(CXh, CXl, Wo, bo, d_out, flag);
}

// Round 9
// 655.335 us; speedup vs baseline: 1.4155x; 1.4062x over previous
//
#include <hip/hip_runtime.h>
#include <hip/hip_bf16.h>

typedef __hip_bfloat16 bf16;
typedef unsigned short u16;
typedef short short8 __attribute__((ext_vector_type(8)));
typedef float f32x4  __attribute__((ext_vector_type(4)));

static __device__ __forceinline__ float b2f(u16 u) {
    union { unsigned int i; float f; } c; c.i = (unsigned int)u << 16; return c.f;
}

// Runtime-dtype load/store: flag==1 -> bf16 inputs, 0 -> fp32 inputs.
static __device__ __forceinline__ float ldf(const void* p, size_t i, int isbf16) {
    return isbf16 ? __bfloat162float(((const bf16*)p)[i]) : ((const float*)p)[i];
}
static __device__ __forceinline__ void stf(void* p, size_t i, float v, int isbf16) {
    if (isbf16) ((bf16*)p)[i] = __float2bfloat16(v);
    else        ((float*)p)[i] = v;
}

// ---- split-bf16: v = hi + lo, both truncated bf16 ----
static __device__ __forceinline__ unsigned packf(float v) {
    unsigned ub = __float_as_uint(v);
    unsigned uh = ub & 0xFFFF0000u;
    float r = v - __uint_as_float(uh);
    return uh | (__float_as_uint(r) >> 16);
}
static __device__ __forceinline__ float unpackf(unsigned u) {
    return __uint_as_float(u & 0xFFFF0000u) + __uint_as_float(u << 16);
}

// unpack 8 packed u32 (two uint4) into hi-plane / lo-plane bf16x8
static __device__ __forceinline__ void upk8(uint4 a, uint4 b, short8& h, short8& l) {
    h = (short8){(short)(a.x >> 16), (short)(a.y >> 16), (short)(a.z >> 16), (short)(a.w >> 16),
                 (short)(b.x >> 16), (short)(b.y >> 16), (short)(b.z >> 16), (short)(b.w >> 16)};
    l = (short8){(short)(a.x), (short)(a.y), (short)(a.z), (short)(a.w),
                 (short)(b.x), (short)(b.y), (short)(b.z), (short)(b.w)};
}

// split 8 fp32 (two float4) into hi/lo bf16x8
static __device__ __forceinline__ void splitf8(float4 a, float4 b, short8& h, short8& l) {
    float vv[8] = {a.x, a.y, a.z, a.w, b.x, b.y, b.z, b.w};
    unsigned hh[8], ll[8];
#pragma unroll
    for (int j = 0; j < 8; j++) {
        unsigned ub = __float_as_uint(vv[j]);
        unsigned uh = ub & 0xFFFF0000u;
        float r = vv[j] - __uint_as_float(uh);
        hh[j] = uh >> 16;
        ll[j] = __float_as_uint(r) >> 16;
    }
    h = (short8){(short)hh[0], (short)hh[1], (short)hh[2], (short)hh[3],
                 (short)hh[4], (short)hh[5], (short)hh[6], (short)hh[7]};
    l = (short8){(short)ll[0], (short)ll[1], (short)ll[2], (short)ll[3],
                 (short)ll[4], (short)ll[5], (short)ll[6], (short)ll[7]};
}

static __device__ __forceinline__ float4 u2f4(uint4 a) {
    return (float4){__uint_as_float(a.x), __uint_as_float(a.y),
                    __uint_as_float(a.z), __uint_as_float(a.w)};
}
static __device__ __forceinline__ short8 u4_s8(uint4 a) {
    return (short8){(short)(a.x & 0xFFFF), (short)(a.x >> 16),
                    (short)(a.y & 0xFFFF), (short)(a.y >> 16),
                    (short)(a.z & 0xFFFF), (short)(a.z >> 16),
                    (short)(a.w & 0xFFFF), (short)(a.w >> 16)};
}

// mode: 0 = raw (fp32/bf16 per flag), 2 = packed u32
template<int MODE>
static __device__ __forceinline__ void load_any(const void* P, size_t e, int f, uint4* r) {
    if (MODE == 2) {
        const uint4* p = (const uint4*)((const unsigned*)P + e);
        r[0] = p[0]; r[1] = p[1]; r[2] = p[2]; r[3] = p[3];
    } else if (f == 0) {
        const uint4* p = (const uint4*)((const float*)P + e);
        r[0] = p[0]; r[1] = p[1]; r[2] = p[2]; r[3] = p[3];
    } else {
        const uint4* p = (const uint4*)((const u16*)P + e);
        r[0] = p[0]; r[1] = p[1];
        r[2] = (uint4){0, 0, 0, 0}; r[3] = (uint4){0, 0, 0, 0};
    }
}
template<int MODE>
static __device__ __forceinline__ void conv_any(const uint4* r, int f,
        short8& h0, short8& h1, short8& l0, short8& l1) {
    if (MODE == 2) {
        upk8(r[0], r[1], h0, l0);
        upk8(r[2], r[3], h1, l1);
    } else if (f == 0) {
        splitf8(u2f4(r[0]), u2f4(r[1]), h0, l0);
        splitf8(u2f4(r[2]), u2f4(r[3]), h1, l1);
    } else {
        h0 = u4_s8(r[0]); h1 = u4_s8(r[1]);
        l0 = (short8){0,0,0,0,0,0,0,0};
        l1 = (short8){0,0,0,0,0,0,0,0};
    }
}

static __device__ __forceinline__ void async_copy16(const void* g, void* l) {
    __builtin_amdgcn_global_load_lds((const __attribute__((address_space(1))) void*)g,
                                     (__attribute__((address_space(3))) void*)l, 16, 0, 0);
}

// ---------------------------------------------------------------------------
// dtype detection (verbatim)
// ---------------------------------------------------------------------------
__global__ void detect_dtype(const unsigned short* __restrict__ x, int n, int* __restrict__ flag)
{
    __shared__ int cnt;
    if (threadIdx.x == 0) cnt = 0;
    __syncthreads();
    int local = 0;
    for (int i = threadIdx.x; i < n; i += blockDim.x) {
        const unsigned int e = (x[i] >> 7) & 0xFF;
        if (e >= 134u) local++;
    }
    atomicAdd(&cnt, local);
    __syncthreads();
    if (threadIdx.x == 0) *flag = (cnt >= 32) ? 0 : 1;
}

// ---------------------------------------------------------------------------
// one-time split of x into hi/lo bf16 planes (memory-bound)
// ---------------------------------------------------------------------------
__global__ __launch_bounds__(256)
void split_x(const void* __restrict__ x, u16* __restrict__ Xh, u16* __restrict__ Xl,
             const int* __restrict__ flagp)
{
    const int f = *flagp;
    const size_t i = ((size_t)blockIdx.x * 256 + threadIdx.x) * 8;
    if (f == 0) {
        const float4* p = (const float4*)((const float*)x + i);
        short8 h, l;
        splitf8(p[0], p[1], h, l);
        *(short8*)(Xh + i) = h;
        *(short8*)(Xl + i) = l;
    } else {
        *(short8*)(Xh + i) = *(const short8*)((const u16*)x + i);
        *(short8*)(Xl + i) = (short8){0,0,0,0,0,0,0,0};
    }
}

// ---------------------------------------------------------------------------
// split-bf16 MFMA GEMM core.  C[m][n] = sum_k A[m][k]*B[n][k] + bias.
// AM/BM operand modes: 0 = raw (fp32/bf16 per flag) -> reg prefetch+split,
//                      1 = pre-split hi/lo planes  -> async global_load_lds,
//                      2 = packed u32              -> reg prefetch+unpack.
// OUT: 1 = packed u32, 2 = stf (dtype per flag).  BROW: bias by output row.
// MFMA inner loop product-outer (distance 16) — measured good for GEMMs.
// ---------------------------------------------------------------------------
template<int AM, int BM, int OUT, int BROW>
static __device__ __forceinline__ void gemm_core(
    const void* __restrict__ Aa, const void* __restrict__ Ab,
    const void* __restrict__ Ba, const void* __restrict__ Bb,
    const void* __restrict__ bias, void* __restrict__ Ca,
    int N, int K, int f, int bx, int by, u16* sm)
{
    u16* AhT = sm;
    u16* AlT = sm + 4096;
    u16* WhT = sm + 8192;
    u16* WlT = sm + 12288;

    const int t = threadIdx.x;
    const int w = t >> 6, lane = t & 63;
    const int wm = w >> 1, wn = w & 1;
    const int lr = lane & 15, quad = lane >> 4;
    const int bm = by * 128, bn = bx * 128;
    const int arow = lane >> 2;          // async map: row within 16-row chunk
    const int acol = (lane & 3) * 8;     // async map: col (u16 units)
    const int srow = t >> 1, scol = (t & 1) * 16;   // reg-staging map

    f32x4 acc[4][4];
#pragma unroll
    for (int i = 0; i < 4; i++)
#pragma unroll
        for (int j = 0; j < 4; j++) acc[i][j] = (f32x4){0.f, 0.f, 0.f, 0.f};

    // reg-side prefetch
    uint4 ra[4], rb[4];
    const size_t aBase = (size_t)(bm + srow) * K + scol;
    const size_t bBase = (size_t)(bn + srow) * K + scol;
    if (AM != 1) load_any<AM>(Aa, aBase, f, ra);
    if (BM != 1) load_any<BM>(Ba, bBase, f, rb);

    for (int k0 = 0; k0 < K; k0 += 32) {
        __syncthreads();
        if (AM == 1) {
#pragma unroll
            for (int c = 2 * w; c < 2 * w + 2; c++) {
                const int row = c * 16 + arow;
                async_copy16((const u16*)Aa + (size_t)(bm + row) * K + k0 + acol, &AhT[c * 512]);
                async_copy16((const u16*)Ab + (size_t)(bm + row) * K + k0 + acol, &AlT[c * 512]);
            }
        } else {
            short8 h0, h1, l0, l1;
            conv_any<AM>(ra, f, h0, h1, l0, l1);
            const int o = srow * 32 + scol;
            *(short8*)&AhT[o] = h0; *(short8*)&AhT[o + 8] = h1;
            *(short8*)&AlT[o] = l0; *(short8*)&AlT[o + 8] = l1;
        }
        if (BM == 1) {
#pragma unroll
            for (int c = 2 * w; c < 2 * w + 2; c++) {
                const int row = c * 16 + arow;
                async_copy16((const u16*)Ba + (size_t)(bn + row) * K + k0 + acol, &WhT[c * 512]);
                async_copy16((const u16*)Bb + (size_t)(bn + row) * K + k0 + acol, &WlT[c * 512]);
            }
        } else {
            short8 h0, h1, l0, l1;
            conv_any<BM>(rb, f, h0, h1, l0, l1);
            const int o = srow * 32 + scol;
            *(short8*)&WhT[o] = h0; *(short8*)&WhT[o + 8] = h1;
            *(short8*)&WlT[o] = l0; *(short8*)&WlT[o + 8] = l1;
        }
        __syncthreads();
        if (k0 + 32 < K) {
            if (AM != 1) load_any<AM>(Aa, aBase + k0 + 32, f, ra);
            if (BM != 1) load_any<BM>(Ba, bBase + k0 + 32, f, rb);
        }

        short8 avh[4], avl[4], bvh[4], bvl[4];
#pragma unroll
        for (int i = 0; i < 4; i++) {
            const int o = (wm * 64 + i * 16 + lr) * 32 + quad * 8;
            avh[i] = *(const short8*)&AhT[o];
            avl[i] = *(const short8*)&AlT[o];
        }
#pragma unroll
        for (int j = 0; j < 4; j++) {
            const int o = (wn * 64 + j * 16 + lr) * 32 + quad * 8;
            bvh[j] = *(const short8*)&WhT[o];
            bvl[j] = *(const short8*)&WlT[o];
        }
        __builtin_amdgcn_s_setprio(1);
        // product-outer: 16 independent MFMAs between dependent acc reuses
#pragma unroll
        for (int i = 0; i < 4; i++)
#pragma unroll
            for (int j = 0; j < 4; j++)
                acc[i][j] = __builtin_amdgcn_mfma_f32_16x16x32_bf16(avl[i], bvh[j], acc[i][j], 0, 0, 0);
#pragma unroll
        for (int i = 0; i < 4; i++)
#pragma unroll
            for (int j = 0; j < 4; j++)
                acc[i][j] = __builtin_amdgcn_mfma_f32_16x16x32_bf16(avh[i], bvl[j], acc[i][j], 0, 0, 0);
#pragma unroll
        for (int i = 0; i < 4; i++)
#pragma unroll
            for (int j = 0; j < 4; j++)
                acc[i][j] = __builtin_amdgcn_mfma_f32_16x16x32_bf16(avh[i], bvh[j], acc[i][j], 0, 0, 0);
        __builtin_amdgcn_s_setprio(0);
    }

#pragma unroll
    for (int j = 0; j < 4; j++) {
        const int col = bn + wn * 64 + j * 16 + lr;
        const float bc = BROW ? 0.f : ldf(bias, col, f);
#pragma unroll
        for (int i = 0; i < 4; i++) {
            const int row0 = bm + wm * 64 + i * 16 + quad * 4;
#pragma unroll
            for (int r = 0; r < 4; r++) {
                const int row = row0 + r;
                const float bb = BROW ? ldf(bias, row, f) : bc;
                const float val = acc[i][j][r] + bb;
                const size_t idx = (size_t)row * N + col;
                if (OUT == 1) ((unsigned*)Ca)[idx] = packf(val);
                else          stf(Ca, idx, val, f);
            }
        }
    }
}

// fused Q (512) + K (128) + V^T (128) projections, x-side async from planes
__global__ __launch_bounds__(256, 3)
void gemm_qkv(const u16* __restrict__ Xh, const u16* __restrict__ Xl,
              const void* __restrict__ Wq, const void* __restrict__ bq, unsigned* __restrict__ Qp,
              const void* __restrict__ Wk, const void* __restrict__ bk, unsigned* __restrict__ Kp,
              const void* __restrict__ Wv, const void* __restrict__ bv, unsigned* __restrict__ Vtp,
              const int* __restrict__ flagp)
{
    __shared__ __align__(16) u16 sm[16384];
    const int f = *flagp;
    const int id = blockIdx.x;
    if (id < 512) {
        gemm_core<1, 0, 1, 0>(Xh, Xl, Wq, nullptr, bq, Qp,
                              2048, 2048, f, id & 15, id >> 4, sm);
    } else if (id < 640) {
        const int v = id - 512;
        gemm_core<1, 0, 1, 0>(Xh, Xl, Wk, nullptr, bk, Kp,
                              512, 2048, f, v & 3, v >> 2, sm);
    } else {
        const int v = id - 640;
        gemm_core<0, 1, 1, 1>(Wv, nullptr, Xh, Xl, bv, Vtp,
                              4096, 2048, f, v >> 2, v & 3, sm);
    }
}

// O-projection: ctx hi/lo planes (async global_load_lds) x raw Wo
__global__ __launch_bounds__(256, 3)
void gemm_o(const u16* __restrict__ Ch, const u16* __restrict__ Cl,
            const void* __restrict__ Wo, const void* __restrict__ bo,
            void* __restrict__ out, const int* __restrict__ flagp)
{
    __shared__ __align__(16) u16 sm[16384];
    gemm_core<1, 0, 2, 0>(Ch, Cl, Wo, nullptr, bo, out,
                          2048, 2048, *flagp, blockIdx.x & 15, blockIdx.x >> 4, sm);
}

// ---------------------------------------------------------------------------
// RMSnorm + RoPE (+gain*scale), in-place on a packed hi|lo tensor.
// ---------------------------------------------------------------------------
__global__ __launch_bounds__(64)
void norm_rope_pk(unsigned* __restrict__ buf, const void* __restrict__ gain,
                  int nheads, float scale, const int* __restrict__ flagp)
{
    const int id = blockIdx.x;
    const int h  = id % nheads;
    const int bs = id / nheads;
    const int s  = bs & 2047;
    unsigned* v = buf + (size_t)bs * nheads * 128 + h * 128;
    const int i = threadIdx.x;

    float t1 = unpackf(v[i]);
    float t2 = unpackf(v[i + 64]);
    float ss = t1 * t1 + t2 * t2;
#pragma unroll
    for (int off = 32; off >= 1; off >>= 1) ss += __shfl_xor(ss, off);
    const float r = rsqrtf(ss * (1.0f / 128.0f) + 1.1920929e-07f);
    t1 *= r; t2 *= r;

    const float inv_freq = exp2f(-(float)i * 0.20762050593046014f);
    const float ph = (float)s * inv_freq;
    float sn, cs;
    __sincosf(ph, &sn, &cs);

    float g = scale;
    if (gain) g *= ldf(gain, h, *flagp);

    v[i]      = packf((t1 * cs + t2 * sn) * g);
    v[i + 64] = packf((-t1 * sn + t2 * cs) * g);
}

// ---------------------------------------------------------------------------
// split-bf16 MFMA flash attention — round-5 kernel body (proven 236 us,
// spill-free) with the plane-C epilogue (round-6, proven spill-free).
// Qp:[4096][2048], Kp:[4096][512], Vtp:[512][4096] (V^T) — packed u32.
// grid (16, H, B): block x handles q-tiles x AND 31-x; 33 tile-units each.
// ---------------------------------------------------------------------------
__global__ __launch_bounds__(256, 2)
void attn3(const unsigned* __restrict__ Qp, const unsigned* __restrict__ Kp,
           const unsigned* __restrict__ Vtp,
           u16* __restrict__ Chg, u16* __restrict__ Clg)
{
    const int S = 2048, D = 2048, KVD = 512, MT = 4096;

    __shared__ __align__(16) u16 Kh[64 * 128], Kl[64 * 128];   // [k][d], XOR-swizzled
    __shared__ __align__(16) u16 Vh[128 * 64], Vl[128 * 64];   // [d][k], XOR-swizzled
    __shared__ __align__(16) u16 Ps[4][16][72];                // per-wave P plane

    const int t = threadIdx.x, w = t >> 6, lane = t & 63;
    const int lr = lane & 15, quad = lane >> 4;
    const int h = blockIdx.y, b = blockIdx.z;
    const int kvh = h >> 2;

    const int qt0 = blockIdx.x;          // 0..15
    const int qt1 = 31 - blockIdx.x;     // 16..31
    const int nt0 = qt0 + 1, nt1 = qt1 + 1;
    const int total = nt0 + nt1;         // 33 for every block

    // staging maps
    const int kr = t >> 2, kq = t & 3;      // K: row 0..63, col-quarter
    const int vd = t >> 1, vh2 = t & 1;     // V^T: row (d) 0..127, col-half
    const unsigned* kg = Kp + (size_t)(b * S + kr) * KVD + kvh * 128 + kq * 32;
    const unsigned* vg = Vtp + (size_t)(kvh * 128 + vd) * MT + b * S + vh2 * 32;
    char* KhB = (char*)Kh; char* KlB = (char*)Kl;
    char* VhB = (char*)Vh; char* VlB = (char*)Vl;

    uint4 kv[8], vv[8];
#define ISSUE_KV(K0)                                                     \
    do {                                                                 \
        _Pragma("unroll")                                                \
        for (int u = 0; u < 8; u++) {                                    \
            kv[u] = *(const uint4*)(kg + (size_t)(K0) * KVD + u * 4);    \
            vv[u] = *(const uint4*)(vg + (K0) + u * 4);                  \
        }                                                                \
    } while (0)

    short8 qh[4], ql[4];
    f32x4 acc[8];
    float mreg[4], lreg[4];
    int q0 = 0, nt = nt0;

    ISSUE_KV(0);

    for (int it = 0; it < total; it++) {
        const int item = (it >= nt0) ? 1 : 0;
        const int kt = item ? (it - nt0) : it;
        if (kt == 0) {
            nt = item ? nt1 : nt0;
            q0 = (item ? qt1 : qt0) * 64;
            const unsigned* qs = Qp + (size_t)(b * S + q0 + w * 16 + lr) * D + h * 128;
#pragma unroll
            for (int kk = 0; kk < 4; kk++) {
                const uint4* p = (const uint4*)(qs + kk * 32 + quad * 8);
                upk8(p[0], p[1], qh[kk], ql[kk]);
            }
#pragma unroll
            for (int dt = 0; dt < 8; dt++) acc[dt] = (f32x4){0.f, 0.f, 0.f, 0.f};
#pragma unroll
            for (int r = 0; r < 4; r++) { mreg[r] = -1e30f; lreg[r] = 0.f; }
        }
        const int k0 = kt * 64;

        __syncthreads();
        // unpack prefetched regs -> swizzled LDS planes (round-3 form, proven)
#pragma unroll
        for (int u2 = 0; u2 < 4; u2++) {
            short8 hh, ll;
            upk8(kv[2 * u2], kv[2 * u2 + 1], hh, ll);
            const int ko = (kr * 256 + kq * 64 + u2 * 16) ^ ((kr & 7) << 4);
            *(short8*)(KhB + ko) = hh;
            *(short8*)(KlB + ko) = ll;
            upk8(vv[2 * u2], vv[2 * u2 + 1], hh, ll);
            const int vo = (vd * 128 + vh2 * 64 + u2 * 16) ^ ((vd & 7) << 4);
            *(short8*)(VhB + vo) = hh;
            *(short8*)(VlB + vo) = ll;
        }
        __syncthreads();

        // issue next tile's gathers; latency hides under compute below
        if (it + 1 < total) {
            const int nk0 = (it + 1 >= nt0) ? (it + 1 - nt0) * 64 : (it + 1) * 64;
            ISSUE_KV(nk0);
        }

        // S = Q*K^T  (3-product split; round-5 fused ordering)
        f32x4 sacc[4];
#pragma unroll
        for (int ct = 0; ct < 4; ct++) sacc[ct] = (f32x4){0.f, 0.f, 0.f, 0.f};
#pragma unroll
        for (int ks = 0; ks < 4; ks++) {
            short8 kbh[4], kbl[4];
#pragma unroll
            for (int ct = 0; ct < 4; ct++) {
                const int row = ct * 16 + lr;
                const int off = (row * 256 + ks * 64 + quad * 16) ^ ((row & 7) << 4);
                kbh[ct] = *(const short8*)(KhB + off);
                kbl[ct] = *(const short8*)(KlB + off);
            }
            __builtin_amdgcn_s_setprio(1);
#pragma unroll
            for (int ct = 0; ct < 4; ct++) {
                sacc[ct] = __builtin_amdgcn_mfma_f32_16x16x32_bf16(ql[ks], kbh[ct], sacc[ct], 0, 0, 0);
                sacc[ct] = __builtin_amdgcn_mfma_f32_16x16x32_bf16(qh[ks], kbl[ct], sacc[ct], 0, 0, 0);
                sacc[ct] = __builtin_amdgcn_mfma_f32_16x16x32_bf16(qh[ks], kbh[ct], sacc[ct], 0, 0, 0);
            }
            __builtin_amdgcn_s_setprio(0);
        }

        // online softmax (branchless); C-layout: row = quad*4+r, col = ct*16+lr
        const bool diag = (kt == nt - 1);
        float p[4][4];
#pragma unroll
        for (int r = 0; r < 4; r++) {
            const int qg = q0 + w * 16 + quad * 4 + r;
            float s0 = sacc[0][r], s1 = sacc[1][r], s2 = sacc[2][r], s3 = sacc[3][r];
            if (diag) {
                if (k0 +  0 + lr > qg) s0 = -1e30f;
                if (k0 + 16 + lr > qg) s1 = -1e30f;
                if (k0 + 32 + lr > qg) s2 = -1e30f;
                if (k0 + 48 + lr > qg) s3 = -1e30f;
            }
            float mt = fmaxf(fmaxf(s0, s1), fmaxf(s2, s3));
#pragma unroll
            for (int off = 1; off < 16; off <<= 1) mt = fmaxf(mt, __shfl_xor(mt, off));
            const float mnew  = fmaxf(mreg[r], mt);
            const float alpha = __expf(mreg[r] - mnew);
            p[r][0] = (s0 <= -1e29f) ? 0.f : __expf(s0 - mnew);
            p[r][1] = (s1 <= -1e29f) ? 0.f : __expf(s1 - mnew);
            p[r][2] = (s2 <= -1e29f) ? 0.f : __expf(s2 - mnew);
            p[r][3] = (s3 <= -1e29f) ? 0.f : __expf(s3 - mnew);
            float ps = p[r][0] + p[r][1] + p[r][2] + p[r][3];
#pragma unroll
            for (int off = 1; off < 16; off <<= 1) ps += __shfl_xor(ps, off);
            lreg[r] = lreg[r] * alpha + ps;
            mreg[r] = mnew;
#pragma unroll
            for (int dt = 0; dt < 8; dt++) acc[dt][r] *= alpha;
        }

        // ---- PV pass 1: P_hi * (V_hi + V_lo), round-5 interleaved form ----
#pragma unroll
        for (int r = 0; r < 4; r++)
#pragma unroll
            for (int ct = 0; ct < 4; ct++)
                Ps[w][quad * 4 + r][ct * 16 + lr] = (u16)(__float_as_uint(p[r][ct]) >> 16);
#pragma unroll
        for (int ks2 = 0; ks2 < 2; ks2++) {
            const short8 pa = *(const short8*)((const char*)&Ps[w][lr][0] + ks2 * 64 + quad * 16);
            __builtin_amdgcn_s_setprio(1);
#pragma unroll
            for (int dt = 0; dt < 8; dt++) {
                const int vrow = dt * 16 + lr;
                const int off = (vrow * 128 + ks2 * 64 + quad * 16) ^ ((vrow & 7) << 4);
                const short8 vbh = *(const short8*)(VhB + off);
                const short8 vbl = *(const short8*)(VlB + off);
                acc[dt] = __builtin_amdgcn_mfma_f32_16x16x32_bf16(pa, vbh, acc[dt], 0, 0, 0);
                acc[dt] = __builtin_amdgcn_mfma_f32_16x16x32_bf16(pa, vbl, acc[dt], 0, 0, 0);
            }
            __builtin_amdgcn_s_setprio(0);
        }
        // ---- PV pass 2: P_lo * V_hi ----
#pragma unroll
        for (int r = 0; r < 4; r++)
#pragma unroll
            for (int ct = 0; ct < 4; ct++) {
                const unsigned ub = __float_as_uint(p[r][ct]);
                const unsigned uh = ub & 0xFFFF0000u;
                const float rr = p[r][ct] - __uint_as_float(uh);
                Ps[w][quad * 4 + r][ct * 16 + lr] = (u16)(__float_as_uint(rr) >> 16);
            }
#pragma unroll
        for (int ks2 = 0; ks2 < 2; ks2++) {
            const short8 pa = *(const short8*)((const char*)&Ps[w][lr][0] + ks2 * 64 + quad * 16);
            __builtin_amdgcn_s_setprio(1);
#pragma unroll
            for (int dt = 0; dt < 8; dt++) {
                const int vrow = dt * 16 + lr;
                const int off = (vrow * 128 + ks2 * 64 + quad * 16) ^ ((vrow & 7) << 4);
                const short8 vbh = *(const short8*)(VhB + off);
                acc[dt] = __builtin_amdgcn_mfma_f32_16x16x32_bf16(pa, vbh, acc[dt], 0, 0, 0);
            }
            __builtin_amdgcn_s_setprio(0);
        }

        // epilogue for the finished item -> hi/lo C planes
        if (kt == nt - 1) {
#pragma unroll
            for (int r = 0; r < 4; r++) {
                const float inv = 1.0f / lreg[r];
                const size_t base = (size_t)(b * S + q0 + w * 16 + quad * 4 + r) * D + h * 128 + lr;
#pragma unroll
                for (int dt = 0; dt < 8; dt++) {
                    const float val = acc[dt][r] * inv;
                    const unsigned ub = __float_as_uint(val);
                    const unsigned uh = ub & 0xFFFF0000u;
                    Chg[base + dt * 16] = (u16)(uh >> 16);
                    Clg[base + dt * 16] = (u16)(__float_as_uint(val - __uint_as_float(uh)) >> 16);
                }
            }
        }
    }
#undef ISSUE_KV
}

// ---------------------------------------------------------------------------
extern "C" void kernel_launch(void* const* d_in, const int* in_sizes, int n_in,
                              void* d_out, int out_size, void* d_ws, size_t ws_size,
                              hipStream_t stream)
{
    const void* x  = d_in[0];
    const void* Wq = d_in[1];
    const void* bq = d_in[2];
    const void* Wk = d_in[3];
    const void* bk = d_in[4];
    const void* Wv = d_in[5];
    const void* bv = d_in[6];
    const void* Wo = d_in[7];
    const void* bo = d_in[8];
    const void* qg = d_in[9];

    const int B = 2, S = 2048, D = 2048, H = 16, KVH = 4, KVD = 512;
    const int M = B * S;   // 4096

    // layout (83.9 MB, flag at the proven offset):
    //   Qp [M][D] u32, Kp [M][KVD] u32, Vtp [KVD][M] u32,
    //   C region: x hi/lo planes (pre-attn) -> ctx hi/lo planes (post-attn)
    unsigned* Qp  = (unsigned*)d_ws;              // [M][D]
    unsigned* Kp  = Qp + (size_t)M * D;           // [M][KVD]
    unsigned* Vtp = Kp + (size_t)M * KVD;         // [KVD][M]  (V^T)
    unsigned* Cp  = Vtp + (size_t)KVD * M;        // [M][D] region
    int* flag = (int*)(Cp + (size_t)M * D);
    u16* CXh = (u16*)Cp;                          // [M][D] hi plane
    u16* CXl = CXh + (size_t)M * D;               // [M][D] lo plane

    detect_dtype<<<1, 256, 0, stream>>>((const unsigned short*)x, 16384, flag);

    // one-time split of x into hi/lo planes (in the C region)
    split_x<<<(M * D) / (256 * 8), 256, 0, stream>>>(x, CXh, CXl, flag);

    // fused Q/K/V^T projections -> packed
    gemm_qkv<<<768, 256, 0, stream>>>(CXh, CXl, Wq, bq, Qp,
                                      Wk, bk, Kp, Wv, bv, Vtp, flag);

    // RMSnorm + RoPE in-place (scale*gain folded into Q)
    norm_rope_pk<<<M * H, 64, 0, stream>>>(Qp, qg, H, 0.08838834764831845f, flag);
    norm_rope_pk<<<M * KVH, 64, 0, stream>>>(Kp, nullptr, KVH, 1.0f, flag);

    // attention: packed Q/K/V^T -> ctx hi/lo planes (over the dead x planes)
    attn3<<<dim3(16, H, B), 256, 0, stream>>>(Qp, Kp, Vtp, CXh, CXl);

    // out = ctx*Wo^T + bo -> d_out (dtype follows input)
    gemm_o<<<512, 256, 0, stream>>>(CXh, CXl, Wo, bo, d_out, flag);
}

// Round 11
// 649.365 us; speedup vs baseline: 1.4285x; 1.0092x over previous
//
#include <hip/hip_runtime.h>
#include <hip/hip_bf16.h>

typedef __hip_bfloat16 bf16;
typedef unsigned short u16;
typedef short short8 __attribute__((ext_vector_type(8)));
typedef float f32x4  __attribute__((ext_vector_type(4)));

static __device__ __forceinline__ float b2f(u16 u) {
    union { unsigned int i; float f; } c; c.i = (unsigned int)u << 16; return c.f;
}

// Runtime-dtype load/store: flag==1 -> bf16 inputs, 0 -> fp32 inputs.
static __device__ __forceinline__ float ldf(const void* p, size_t i, int isbf16) {
    return isbf16 ? __bfloat162float(((const bf16*)p)[i]) : ((const float*)p)[i];
}
static __device__ __forceinline__ void stf(void* p, size_t i, float v, int isbf16) {
    if (isbf16) ((bf16*)p)[i] = __float2bfloat16(v);
    else        ((float*)p)[i] = v;
}

// ---- split-bf16: v = hi + lo, both truncated bf16 ----
static __device__ __forceinline__ unsigned packf(float v) {
    unsigned ub = __float_as_uint(v);
    unsigned uh = ub & 0xFFFF0000u;
    float r = v - __uint_as_float(uh);
    return uh | (__float_as_uint(r) >> 16);
}
static __device__ __forceinline__ float unpackf(unsigned u) {
    return __uint_as_float(u & 0xFFFF0000u) + __uint_as_float(u << 16);
}

// unpack 8 packed u32 (two uint4) into hi-plane / lo-plane bf16x8
static __device__ __forceinline__ void upk8(uint4 a, uint4 b, short8& h, short8& l) {
    h = (short8){(short)(a.x >> 16), (short)(a.y >> 16), (short)(a.z >> 16), (short)(a.w >> 16),
                 (short)(b.x >> 16), (short)(b.y >> 16), (short)(b.z >> 16), (short)(b.w >> 16)};
    l = (short8){(short)(a.x), (short)(a.y), (short)(a.z), (short)(a.w),
                 (short)(b.x), (short)(b.y), (short)(b.z), (short)(b.w)};
}

// split 8 fp32 (two float4) into hi/lo bf16x8
static __device__ __forceinline__ void splitf8(float4 a, float4 b, short8& h, short8& l) {
    float vv[8] = {a.x, a.y, a.z, a.w, b.x, b.y, b.z, b.w};
    unsigned hh[8], ll[8];
#pragma unroll
    for (int j = 0; j < 8; j++) {
        unsigned ub = __float_as_uint(vv[j]);
        unsigned uh = ub & 0xFFFF0000u;
        float r = vv[j] - __uint_as_float(uh);
        hh[j] = uh >> 16;
        ll[j] = __float_as_uint(r) >> 16;
    }
    h = (short8){(short)hh[0], (short)hh[1], (short)hh[2], (short)hh[3],
                 (short)hh[4], (short)hh[5], (short)hh[6], (short)hh[7]};
    l = (short8){(short)ll[0], (short)ll[1], (short)ll[2], (short)ll[3],
                 (short)ll[4], (short)ll[5], (short)ll[6], (short)ll[7]};
}

static __device__ __forceinline__ float4 u2f4(uint4 a) {
    return (float4){__uint_as_float(a.x), __uint_as_float(a.y),
                    __uint_as_float(a.z), __uint_as_float(a.w)};
}
static __device__ __forceinline__ short8 u4_s8(uint4 a) {
    return (short8){(short)(a.x & 0xFFFF), (short)(a.x >> 16),
                    (short)(a.y & 0xFFFF), (short)(a.y >> 16),
                    (short)(a.z & 0xFFFF), (short)(a.z >> 16),
                    (short)(a.w & 0xFFFF), (short)(a.w >> 16)};
}

// mode: 0 = raw (fp32/bf16 per flag), 2 = packed u32
template<int MODE>
static __device__ __forceinline__ void load_any(const void* P, size_t e, int f, uint4* r) {
    if (MODE == 2) {
        const uint4* p = (const uint4*)((const unsigned*)P + e);
        r[0] = p[0]; r[1] = p[1]; r[2] = p[2]; r[3] = p[3];
    } else if (f == 0) {
        const uint4* p = (const uint4*)((const float*)P + e);
        r[0] = p[0]; r[1] = p[1]; r[2] = p[2]; r[3] = p[3];
    } else {
        const uint4* p = (const uint4*)((const u16*)P + e);
        r[0] = p[0]; r[1] = p[1];
        r[2] = (uint4){0, 0, 0, 0}; r[3] = (uint4){0, 0, 0, 0};
    }
}
template<int MODE>
static __device__ __forceinline__ void conv_any(const uint4* r, int f,
        short8& h0, short8& h1, short8& l0, short8& l1) {
    if (MODE == 2) {
        upk8(r[0], r[1], h0, l0);
        upk8(r[2], r[3], h1, l1);
    } else if (f == 0) {
        splitf8(u2f4(r[0]), u2f4(r[1]), h0, l0);
        splitf8(u2f4(r[2]), u2f4(r[3]), h1, l1);
    } else {
        h0 = u4_s8(r[0]); h1 = u4_s8(r[1]);
        l0 = (short8){0,0,0,0,0,0,0,0};
        l1 = (short8){0,0,0,0,0,0,0,0};
    }
}

static __device__ __forceinline__ void async_copy16(const void* g, void* l) {
    __builtin_amdgcn_global_load_lds((const __attribute__((address_space(1))) void*)g,
                                     (__attribute__((address_space(3))) void*)l, 16, 0, 0);
}

// ---------------------------------------------------------------------------
// dtype detection (verbatim)
// ---------------------------------------------------------------------------
__global__ void detect_dtype(const unsigned short* __restrict__ x, int n, int* __restrict__ flag)
{
    __shared__ int cnt;
    if (threadIdx.x == 0) cnt = 0;
    __syncthreads();
    int local = 0;
    for (int i = threadIdx.x; i < n; i += blockDim.x) {
        const unsigned int e = (x[i] >> 7) & 0xFF;
        if (e >= 134u) local++;
    }
    atomicAdd(&cnt, local);
    __syncthreads();
    if (threadIdx.x == 0) *flag = (cnt >= 32) ? 0 : 1;
}

// ---------------------------------------------------------------------------
// one-time split of x into hi/lo bf16 planes (memory-bound)
// ---------------------------------------------------------------------------
__global__ __launch_bounds__(256)
void split_x(const void* __restrict__ x, u16* __restrict__ Xh, u16* __restrict__ Xl,
             const int* __restrict__ flagp)
{
    const int f = *flagp;
    const size_t i = ((size_t)blockIdx.x * 256 + threadIdx.x) * 8;
    if (f == 0) {
        const float4* p = (const float4*)((const float*)x + i);
        short8 h, l;
        splitf8(p[0], p[1], h, l);
        *(short8*)(Xh + i) = h;
        *(short8*)(Xl + i) = l;
    } else {
        *(short8*)(Xh + i) = *(const short8*)((const u16*)x + i);
        *(short8*)(Xl + i) = (short8){0,0,0,0,0,0,0,0};
    }
}

// ---------------------------------------------------------------------------
// split-bf16 MFMA GEMM core (LOCKED inner structure — rounds 4/7/8 showed any
// staging-path change spills the prefetch regs to scratch; do not touch).
// C[m][n] = sum_k A[m][k]*B[n][k] + bias.
// AM/BM: 0 = raw (fp32/bf16 per flag), 1 = pre-split planes (async), 2 = packed.
// OUT: 1 = packed u32, 2 = stf.  BROW: bias by output row.
// ---------------------------------------------------------------------------
template<int AM, int BM, int OUT, int BROW>
static __device__ __forceinline__ void gemm_core(
    const void* __restrict__ Aa, const void* __restrict__ Ab,
    const void* __restrict__ Ba, const void* __restrict__ Bb,
    const void* __restrict__ bias, void* __restrict__ Ca,
    int N, int K, int f, int bx, int by, u16* sm)
{
    u16* AhT = sm;
    u16* AlT = sm + 4096;
    u16* WhT = sm + 8192;
    u16* WlT = sm + 12288;

    const int t = threadIdx.x;
    const int w = t >> 6, lane = t & 63;
    const int wm = w >> 1, wn = w & 1;
    const int lr = lane & 15, quad = lane >> 4;
    const int bm = by * 128, bn = bx * 128;
    const int arow = lane >> 2;          // async map: row within 16-row chunk
    const int acol = (lane & 3) * 8;     // async map: col (u16 units)
    const int srow = t >> 1, scol = (t & 1) * 16;   // reg-staging map

    f32x4 acc[4][4];
#pragma unroll
    for (int i = 0; i < 4; i++)
#pragma unroll
        for (int j = 0; j < 4; j++) acc[i][j] = (f32x4){0.f, 0.f, 0.f, 0.f};

    // reg-side prefetch
    uint4 ra[4], rb[4];
    const size_t aBase = (size_t)(bm + srow) * K + scol;
    const size_t bBase = (size_t)(bn + srow) * K + scol;
    if (AM != 1) load_any<AM>(Aa, aBase, f, ra);
    if (BM != 1) load_any<BM>(Ba, bBase, f, rb);

    for (int k0 = 0; k0 < K; k0 += 32) {
        __syncthreads();
        if (AM == 1) {
#pragma unroll
            for (int c = 2 * w; c < 2 * w + 2; c++) {
                const int row = c * 16 + arow;
                async_copy16((const u16*)Aa + (size_t)(bm + row) * K + k0 + acol, &AhT[c * 512]);
                async_copy16((const u16*)Ab + (size_t)(bm + row) * K + k0 + acol, &AlT[c * 512]);
            }
        } else {
            short8 h0, h1, l0, l1;
            conv_any<AM>(ra, f, h0, h1, l0, l1);
            const int o = srow * 32 + scol;
            *(short8*)&AhT[o] = h0; *(short8*)&AhT[o + 8] = h1;
            *(short8*)&AlT[o] = l0; *(short8*)&AlT[o + 8] = l1;
        }
        if (BM == 1) {
#pragma unroll
            for (int c = 2 * w; c < 2 * w + 2; c++) {
                const int row = c * 16 + arow;
                async_copy16((const u16*)Ba + (size_t)(bn + row) * K + k0 + acol, &WhT[c * 512]);
                async_copy16((const u16*)Bb + (size_t)(bn + row) * K + k0 + acol, &WlT[c * 512]);
            }
        } else {
            short8 h0, h1, l0, l1;
            conv_any<BM>(rb, f, h0, h1, l0, l1);
            const int o = srow * 32 + scol;
            *(short8*)&WhT[o] = h0; *(short8*)&WhT[o + 8] = h1;
            *(short8*)&WlT[o] = l0; *(short8*)&WlT[o + 8] = l1;
        }
        __syncthreads();
        if (k0 + 32 < K) {
            if (AM != 1) load_any<AM>(Aa, aBase + k0 + 32, f, ra);
            if (BM != 1) load_any<BM>(Ba, bBase + k0 + 32, f, rb);
        }

        short8 avh[4], avl[4], bvh[4], bvl[4];
#pragma unroll
        for (int i = 0; i < 4; i++) {
            const int o = (wm * 64 + i * 16 + lr) * 32 + quad * 8;
            avh[i] = *(const short8*)&AhT[o];
            avl[i] = *(const short8*)&AlT[o];
        }
#pragma unroll
        for (int j = 0; j < 4; j++) {
            const int o = (wn * 64 + j * 16 + lr) * 32 + quad * 8;
            bvh[j] = *(const short8*)&WhT[o];
            bvl[j] = *(const short8*)&WlT[o];
        }
        __builtin_amdgcn_s_setprio(1);
        // product-outer: 16 independent MFMAs between dependent acc reuses
#pragma unroll
        for (int i = 0; i < 4; i++)
#pragma unroll
            for (int j = 0; j < 4; j++)
                acc[i][j] = __builtin_amdgcn_mfma_f32_16x16x32_bf16(avl[i], bvh[j], acc[i][j], 0, 0, 0);
#pragma unroll
        for (int i = 0; i < 4; i++)
#pragma unroll
            for (int j = 0; j < 4; j++)
                acc[i][j] = __builtin_amdgcn_mfma_f32_16x16x32_bf16(avh[i], bvl[j], acc[i][j], 0, 0, 0);
#pragma unroll
        for (int i = 0; i < 4; i++)
#pragma unroll
            for (int j = 0; j < 4; j++)
                acc[i][j] = __builtin_amdgcn_mfma_f32_16x16x32_bf16(avh[i], bvh[j], acc[i][j], 0, 0, 0);
        __builtin_amdgcn_s_setprio(0);
    }

#pragma unroll
    for (int j = 0; j < 4; j++) {
        const int col = bn + wn * 64 + j * 16 + lr;
        const float bc = BROW ? 0.f : ldf(bias, col, f);
#pragma unroll
        for (int i = 0; i < 4; i++) {
            const int row0 = bm + wm * 64 + i * 16 + quad * 4;
#pragma unroll
            for (int r = 0; r < 4; r++) {
                const int row = row0 + r;
                const float bb = BROW ? ldf(bias, row, f) : bc;
                const float val = acc[i][j][r] + bb;
                const size_t idx = (size_t)row * N + col;
                if (OUT == 1) ((unsigned*)Ca)[idx] = packf(val);
                else          stf(Ca, idx, val, f);
            }
        }
    }
}

// fused Q (512) + K (128) + V^T (128) projections with XCD-aware block
// remap (T1): blocks dispatch round-robin to XCDs (XCD = blockIdx % 8), so
// grouping same-W-panel blocks at equal (mod 8) indices makes each XCD's
// 1-2 MB weight panel L2-resident, removing the dominant redundant fetch.
__global__ __launch_bounds__(256, 3)
void gemm_qkv(const u16* __restrict__ Xh, const u16* __restrict__ Xl,
              const void* __restrict__ Wq, const void* __restrict__ bq, unsigned* __restrict__ Qp,
              const void* __restrict__ Wk, const void* __restrict__ bk, unsigned* __restrict__ Kp,
              const void* __restrict__ Wv, const void* __restrict__ bv, unsigned* __restrict__ Vtp,
              const int* __restrict__ flagp)
{
    __shared__ __align__(16) u16 sm[16384];
    const int f = *flagp;
    const int id = blockIdx.x;
    if (id < 512) {
        // XCD g owns bx in {2g, 2g+1}: 2 MB Wq panel cached in its L2
        const int g = id & 7, k = id >> 3;
        gemm_core<1, 0, 1, 0>(Xh, Xl, Wq, nullptr, bq, Qp,
                              2048, 2048, f, 2 * g + (k & 1), k >> 1, sm);
    } else if (id < 640) {
        // XCD g owns Wk panel g>>1 (1 MB cached)
        const int v = id - 512;
        const int g = v & 7, k = v >> 3;
        gemm_core<1, 0, 1, 0>(Xh, Xl, Wk, nullptr, bk, Kp,
                              512, 2048, f, g >> 1, (g & 1) * 16 + k, sm);
    } else {
        // XCD g owns Wv panel g>>1 (A-side raw operand, 1 MB cached)
        const int v = id - 640;
        const int g = v & 7, k = v >> 3;
        gemm_core<0, 1, 1, 1>(Wv, nullptr, Xh, Xl, bv, Vtp,
                              4096, 2048, f, (g & 1) * 16 + k, g >> 1, sm);
    }
}

// O-projection: ctx hi/lo planes (async) x raw Wo, same XCD remap as Q.
__global__ __launch_bounds__(256, 3)
void gemm_o(const u16* __restrict__ Ch, const u16* __restrict__ Cl,
            const void* __restrict__ Wo, const void* __restrict__ bo,
            void* __restrict__ out, const int* __restrict__ flagp)
{
    __shared__ __align__(16) u16 sm[16384];
    const int id = blockIdx.x;
    const int g = id & 7, k = id >> 3;
    gemm_core<1, 0, 2, 0>(Ch, Cl, Wo, nullptr, bo, out,
                          2048, 2048, *flagp, 2 * g + (k & 1), k >> 1, sm);
}

// ---------------------------------------------------------------------------
// RMSnorm + RoPE (+gain*scale), in-place on a packed hi|lo tensor.
// ---------------------------------------------------------------------------
__global__ __launch_bounds__(64)
void norm_rope_pk(unsigned* __restrict__ buf, const void* __restrict__ gain,
                  int nheads, float scale, const int* __restrict__ flagp)
{
    const int id = blockIdx.x;
    const int h  = id % nheads;
    const int bs = id / nheads;
    const int s  = bs & 2047;
    unsigned* v = buf + (size_t)bs * nheads * 128 + h * 128;
    const int i = threadIdx.x;

    float t1 = unpackf(v[i]);
    float t2 = unpackf(v[i + 64]);
    float ss = t1 * t1 + t2 * t2;
#pragma unroll
    for (int off = 32; off >= 1; off >>= 1) ss += __shfl_xor(ss, off);
    const float r = rsqrtf(ss * (1.0f / 128.0f) + 1.1920929e-07f);
    t1 *= r; t2 *= r;

    const float inv_freq = exp2f(-(float)i * 0.20762050593046014f);
    const float ph = (float)s * inv_freq;
    float sn, cs;
    __sincosf(ph, &sn, &cs);

    float g = scale;
    if (gain) g *= ldf(gain, h, *flagp);

    v[i]      = packf((t1 * cs + t2 * sn) * g);
    v[i + 64] = packf((-t1 * sn + t2 * cs) * g);
}

// ---------------------------------------------------------------------------
// split-bf16 MFMA flash attention — round-5 body (proven 236 us, spill-free;
// staging path LOCKED), plane-C epilogue, XCD-aware 1-D grid:
// XCD g owns all 64 blocks of one (b, kvh) -> that group's 2 MB K+V slice is
// L2-resident; K/V fetched from HBM once per XCD instead of re-streamed.
// Qp:[4096][2048], Kp:[4096][512], Vtp:[512][4096] (V^T) — packed u32.
// Each block handles q-tiles x and 31-x (33 uniform tile-units).
// ---------------------------------------------------------------------------
__global__ __launch_bounds__(256, 2)
void attn3(const unsigned* __restrict__ Qp, const unsigned* __restrict__ Kp,
           const unsigned* __restrict__ Vtp,
           u16* __restrict__ Chg, u16* __restrict__ Clg)
{
    const int S = 2048, D = 2048, KVD = 512, MT = 4096;

    __shared__ __align__(16) u16 Kh[64 * 128], Kl[64 * 128];   // [k][d], XOR-swizzled
    __shared__ __align__(16) u16 Vh[128 * 64], Vl[128 * 64];   // [d][k], XOR-swizzled
    __shared__ __align__(16) u16 Ps[4][16][72];                // per-wave P plane

    const int t = threadIdx.x, w = t >> 6, lane = t & 63;
    const int lr = lane & 15, quad = lane >> 4;

    // XCD decode: g = blockIdx % 8 selects (b, kvh); 64 blocks per group.
    const int bid = blockIdx.x;
    const int g8 = bid & 7, kk0 = bid >> 3;     // kk0: 0..63
    const int b   = g8 >> 2;                     // batch 0..1
    const int kvh = g8 & 3;                      // kv head 0..3
    const int h   = kvh * 4 + (kk0 >> 4);        // head (GQA: h>>2 == kvh)

    const int qt0 = kk0 & 15;            // 0..15
    const int qt1 = 31 - qt0;            // 16..31
    const int nt0 = qt0 + 1, nt1 = qt1 + 1;
    const int total = nt0 + nt1;         // 33 for every block

    // staging maps
    const int kr = t >> 2, kq = t & 3;      // K: row 0..63, col-quarter
    const int vd = t >> 1, vh2 = t & 1;     // V^T: row (d) 0..127, col-half
    const unsigned* kg = Kp + (size_t)(b * S + kr) * KVD + kvh * 128 + kq * 32;
    const unsigned* vg = Vtp + (size_t)(kvh * 128 + vd) * MT + b * S + vh2 * 32;
    char* KhB = (char*)Kh; char* KlB = (char*)Kl;
    char* VhB = (char*)Vh; char* VlB = (char*)Vl;

    uint4 kv[8], vv[8];
#define ISSUE_KV(K0)                                                     \
    do {                                                                 \
        _Pragma("unroll")                                                \
        for (int u = 0; u < 8; u++) {                                    \
            kv[u] = *(const uint4*)(kg + (size_t)(K0) * KVD + u * 4);    \
            vv[u] = *(const uint4*)(vg + (K0) + u * 4);                  \
        }                                                                \
    } while (0)

    short8 qh[4], ql[4];
    f32x4 acc[8];
    float mreg[4], lreg[4];
    int q0 = 0, nt = nt0;

    ISSUE_KV(0);

    for (int it = 0; it < total; it++) {
        const int item = (it >= nt0) ? 1 : 0;
        const int kt = item ? (it - nt0) : it;
        if (kt == 0) {
            nt = item ? nt1 : nt0;
            q0 = (item ? qt1 : qt0) * 64;
            const unsigned* qs = Qp + (size_t)(b * S + q0 + w * 16 + lr) * D + h * 128;
#pragma unroll
            for (int kk = 0; kk < 4; kk++) {
                const uint4* p = (const uint4*)(qs + kk * 32 + quad * 8);
                upk8(p[0], p[1], qh[kk], ql[kk]);
            }
#pragma unroll
            for (int dt = 0; dt < 8; dt++) acc[dt] = (f32x4){0.f, 0.f, 0.f, 0.f};
#pragma unroll
            for (int r = 0; r < 4; r++) { mreg[r] = -1e30f; lreg[r] = 0.f; }
        }
        const int k0 = kt * 64;

        __syncthreads();
        // unpack prefetched regs -> swizzled LDS planes (round-3 form, proven)
#pragma unroll
        for (int u2 = 0; u2 < 4; u2++) {
            short8 hh, ll;
            upk8(kv[2 * u2], kv[2 * u2 + 1], hh, ll);
            const int ko = (kr * 256 + kq * 64 + u2 * 16) ^ ((kr & 7) << 4);
            *(short8*)(KhB + ko) = hh;
            *(short8*)(KlB + ko) = ll;
            upk8(vv[2 * u2], vv[2 * u2 + 1], hh, ll);
            const int vo = (vd * 128 + vh2 * 64 + u2 * 16) ^ ((vd & 7) << 4);
            *(short8*)(VhB + vo) = hh;
            *(short8*)(VlB + vo) = ll;
        }
        __syncthreads();

        // issue next tile's gathers; latency hides under compute below
        if (it + 1 < total) {
            const int nk0 = (it + 1 >= nt0) ? (it + 1 - nt0) * 64 : (it + 1) * 64;
            ISSUE_KV(nk0);
        }

        // S = Q*K^T  (3-product split; round-5 fused ordering)
        f32x4 sacc[4];
#pragma unroll
        for (int ct = 0; ct < 4; ct++) sacc[ct] = (f32x4){0.f, 0.f, 0.f, 0.f};
#pragma unroll
        for (int ks = 0; ks < 4; ks++) {
            short8 kbh[4], kbl[4];
#pragma unroll
            for (int ct = 0; ct < 4; ct++) {
                const int row = ct * 16 + lr;
                const int off = (row * 256 + ks * 64 + quad * 16) ^ ((row & 7) << 4);
                kbh[ct] = *(const short8*)(KhB + off);
                kbl[ct] = *(const short8*)(KlB + off);
            }
            __builtin_amdgcn_s_setprio(1);
#pragma unroll
            for (int ct = 0; ct < 4; ct++) {
                sacc[ct] = __builtin_amdgcn_mfma_f32_16x16x32_bf16(ql[ks], kbh[ct], sacc[ct], 0, 0, 0);
                sacc[ct] = __builtin_amdgcn_mfma_f32_16x16x32_bf16(qh[ks], kbl[ct], sacc[ct], 0, 0, 0);
                sacc[ct] = __builtin_amdgcn_mfma_f32_16x16x32_bf16(qh[ks], kbh[ct], sacc[ct], 0, 0, 0);
            }
            __builtin_amdgcn_s_setprio(0);
        }

        // online softmax (branchless); C-layout: row = quad*4+r, col = ct*16+lr
        const bool diag = (kt == nt - 1);
        float p[4][4];
#pragma unroll
        for (int r = 0; r < 4; r++) {
            const int qg = q0 + w * 16 + quad * 4 + r;
            float s0 = sacc[0][r], s1 = sacc[1][r], s2 = sacc[2][r], s3 = sacc[3][r];
            if (diag) {
                if (k0 +  0 + lr > qg) s0 = -1e30f;
                if (k0 + 16 + lr > qg) s1 = -1e30f;
                if (k0 + 32 + lr > qg) s2 = -1e30f;
                if (k0 + 48 + lr > qg) s3 = -1e30f;
            }
            float mt = fmaxf(fmaxf(s0, s1), fmaxf(s2, s3));
#pragma unroll
            for (int off = 1; off < 16; off <<= 1) mt = fmaxf(mt, __shfl_xor(mt, off));
            const float mnew  = fmaxf(mreg[r], mt);
            const float alpha = __expf(mreg[r] - mnew);
            p[r][0] = (s0 <= -1e29f) ? 0.f : __expf(s0 - mnew);
            p[r][1] = (s1 <= -1e29f) ? 0.f : __expf(s1 - mnew);
            p[r][2] = (s2 <= -1e29f) ? 0.f : __expf(s2 - mnew);
            p[r][3] = (s3 <= -1e29f) ? 0.f : __expf(s3 - mnew);
            float ps = p[r][0] + p[r][1] + p[r][2] + p[r][3];
#pragma unroll
            for (int off = 1; off < 16; off <<= 1) ps += __shfl_xor(ps, off);
            lreg[r] = lreg[r] * alpha + ps;
            mreg[r] = mnew;
#pragma unroll
            for (int dt = 0; dt < 8; dt++) acc[dt][r] *= alpha;
        }

        // ---- PV pass 1: P_hi * (V_hi + V_lo), round-5 interleaved form ----
#pragma unroll
        for (int r = 0; r < 4; r++)
#pragma unroll
            for (int ct = 0; ct < 4; ct++)
                Ps[w][quad * 4 + r][ct * 16 + lr] = (u16)(__float_as_uint(p[r][ct]) >> 16);
#pragma unroll
        for (int ks2 = 0; ks2 < 2; ks2++) {
            const short8 pa = *(const short8*)((const char*)&Ps[w][lr][0] + ks2 * 64 + quad * 16);
            __builtin_amdgcn_s_setprio(1);
#pragma unroll
            for (int dt = 0; dt < 8; dt++) {
                const int vrow = dt * 16 + lr;
                const int off = (vrow * 128 + ks2 * 64 + quad * 16) ^ ((vrow & 7) << 4);
                const short8 vbh = *(const short8*)(VhB + off);
                const short8 vbl = *(const short8*)(VlB + off);
                acc[dt] = __builtin_amdgcn_mfma_f32_16x16x32_bf16(pa, vbh, acc[dt], 0, 0, 0);
                acc[dt] = __builtin_amdgcn_mfma_f32_16x16x32_bf16(pa, vbl, acc[dt], 0, 0, 0);
            }
            __builtin_amdgcn_s_setprio(0);
        }
        // ---- PV pass 2: P_lo * V_hi ----
#pragma unroll
        for (int r = 0; r < 4; r++)
#pragma unroll
            for (int ct = 0; ct < 4; ct++) {
                const unsigned ub = __float_as_uint(p[r][ct]);
                const unsigned uh = ub & 0xFFFF0000u;
                const float rr = p[r][ct] - __uint_as_float(uh);
                Ps[w][quad * 4 + r][ct * 16 + lr] = (u16)(__float_as_uint(rr) >> 16);
            }
#pragma unroll
        for (int ks2 = 0; ks2 < 2; ks2++) {
            const short8 pa = *(const short8*)((const char*)&Ps[w][lr][0] + ks2 * 64 + quad * 16);
            __builtin_amdgcn_s_setprio(1);
#pragma unroll
            for (int dt = 0; dt < 8; dt++) {
                const int vrow = dt * 16 + lr;
                const int off = (vrow * 128 + ks2 * 64 + quad * 16) ^ ((vrow & 7) << 4);
                const short8 vbh = *(const short8*)(VhB + off);
                acc[dt] = __builtin_amdgcn_mfma_f32_16x16x32_bf16(pa, vbh, acc[dt], 0, 0, 0);
            }
            __builtin_amdgcn_s_setprio(0);
        }

        // epilogue for the finished item -> hi/lo C planes
        if (kt == nt - 1) {
#pragma unroll
            for (int r = 0; r < 4; r++) {
                const float inv = 1.0f / lreg[r];
                const size_t base = (size_t)(b * S + q0 + w * 16 + quad * 4 + r) * D + h * 128 + lr;
#pragma unroll
                for (int dt = 0; dt < 8; dt++) {
                    const float val = acc[dt][r] * inv;
                    const unsigned ub = __float_as_uint(val);
                    const unsigned uh = ub & 0xFFFF0000u;
                    Chg[base + dt * 16] = (u16)(uh >> 16);
                    Clg[base + dt * 16] = (u16)(__float_as_uint(val - __uint_as_float(uh)) >> 16);
                }
            }
        }
    }
#undef ISSUE_KV
}

// ---------------------------------------------------------------------------
extern "C" void kernel_launch(void* const* d_in, const int* in_sizes, int n_in,
                              void* d_out, int out_size, void* d_ws, size_t ws_size,
                              hipStream_t stream)
{
    const void* x  = d_in[0];
    const void* Wq = d_in[1];
    const void* bq = d_in[2];
    const void* Wk = d_in[3];
    const void* bk = d_in[4];
    const void* Wv = d_in[5];
    const void* bv = d_in[6];
    const void* Wo = d_in[7];
    const void* bo = d_in[8];
    const void* qg = d_in[9];

    const int B = 2, S = 2048, D = 2048, H = 16, KVH = 4, KVD = 512;
    const int M = B * S;   // 4096

    // layout (83.9 MB, flag at the proven offset):
    //   Qp [M][D] u32, Kp [M][KVD] u32, Vtp [KVD][M] u32,
    //   C region: x hi/lo planes (pre-attn) -> ctx hi/lo planes (post-attn)
    unsigned* Qp  = (unsigned*)d_ws;              // [M][D]
    unsigned* Kp  = Qp + (size_t)M * D;           // [M][KVD]
    unsigned* Vtp = Kp + (size_t)M * KVD;         // [KVD][M]  (V^T)
    unsigned* Cp  = Vtp + (size_t)KVD * M;        // [M][D] region
    int* flag = (int*)(Cp + (size_t)M * D);
    u16* CXh = (u16*)Cp;                          // [M][D] hi plane
    u16* CXl = CXh + (size_t)M * D;               // [M][D] lo plane

    detect_dtype<<<1, 256, 0, stream>>>((const unsigned short*)x, 16384, flag);

    // one-time split of x into hi/lo planes (in the C region)
    split_x<<<(M * D) / (256 * 8), 256, 0, stream>>>(x, CXh, CXl, flag);

    // fused Q/K/V^T projections -> packed (XCD-remapped)
    gemm_qkv<<<768, 256, 0, stream>>>(CXh, CXl, Wq, bq, Qp,
                                      Wk, bk, Kp, Wv, bv, Vtp, flag);

    // RMSnorm + RoPE in-place (scale*gain folded into Q)
    norm_rope_pk<<<M * H, 64, 0, stream>>>(Qp, qg, H, 0.08838834764831845f, flag);
    norm_rope_pk<<<M * KVH, 64, 0, stream>>>(Kp, nullptr, KVH, 1.0f, flag);

    // attention (XCD-remapped 1-D grid): packed Q/K/V^T -> ctx hi/lo planes
    attn3<<<512, 256, 0, stream>>>(Qp, Kp, Vtp, CXh, CXl);

    // out = ctx*Wo^T + bo -> d_out (dtype follows input, XCD-remapped)
    gemm_o<<<512, 256, 0, stream>>>(CXh, CXl, Wo, bo, d_out, flag);
}